// Round 1
// baseline (1307.188 us; speedup 1.0000x reference)
//
#include <hip/hip_runtime.h>
#include <math.h>

// Problem constants
#define BZ 2
#define HH 56
#define WW 56
#define LL 3136      // 56*56
#define CC 96        // DIM
#define DI 192       // DINNER
#define NS 16        // DSTATE
#define RR 6         // DTRANK
#define NT 49        // LL/64

// Workspace layout (floats)
#define OFF_CONV   0
#define OFF_XMRAW  602112
#define OFF_Z      1806336
#define OFF_V1     3010560
#define OFF_V2     4214784
#define OFF_DT     5419008
#define OFF_BS     10235904
#define OFF_CS     10637312
#define OFF_Y      11038720
#define OFF_Y13    15855616
#define OFF_T      18264064
#define OFF_W2     19468288
// total 19486720 floats = ~78 MB

__device__ __forceinline__ float softplusf(float x) {
    if (x > 20.f) return x;
    return log1pf(__expf(x));
}

// ---------------- K0: W2[o][d] = sum_j fus_w[o][96+j] * out_proj_w[j][d] ----------------
__global__ __launch_bounds__(64) void k0_w2(const float* __restrict__ fus_w,
                                            const float* __restrict__ opw,
                                            float* __restrict__ W2) {
    int i = blockIdx.x * 64 + threadIdx.x;   // 96*192 = 18432
    if (i >= CC * DI) return;
    int o = i / DI, d = i % DI;
    float acc = 0.f;
    for (int j = 0; j < CC; ++j)
        acc += fus_w[o * DI + CC + j] * opw[j * DI + d];
    W2[i] = acc;
}

// ---------------- K1: conv path -> conv_out (B,L,96) NHWC ----------------
__global__ __launch_bounds__(256) void k1_conv(const float* __restrict__ x,
    const float* __restrict__ dw_w, const float* __restrict__ dw_b,
    const float* __restrict__ bn1_g, const float* __restrict__ bn1_b,
    const float* __restrict__ bn1_m, const float* __restrict__ bn1_v,
    const float* __restrict__ pw_w, const float* __restrict__ pw_b,
    const float* __restrict__ bn2_g, const float* __restrict__ bn2_b,
    const float* __restrict__ bn2_m, const float* __restrict__ bn2_v,
    float* __restrict__ conv_out) {
    int bh = blockIdx.x;
    int b = bh / HH, h = bh % HH;
    __shared__ float row[WW * CC];        // 21504 B
    __shared__ float pwl[CC * 97];        // 37248 B
    int t = threadIdx.x;
    for (int e = t; e < CC * CC; e += 256) {
        int o = e / CC, c = e % CC;
        pwl[o * 97 + c] = pw_w[e];
    }
    for (int e = t; e < WW * CC; e += 256) {
        int w = e / CC, c = e % CC;
        float acc = dw_b[c];
        #pragma unroll
        for (int dy = -1; dy <= 1; ++dy) {
            int hh = h + dy; if (hh < 0 || hh >= HH) continue;
            #pragma unroll
            for (int dx = -1; dx <= 1; ++dx) {
                int ww = w + dx; if (ww < 0 || ww >= WW) continue;
                acc += x[((b * HH + hh) * WW + ww) * CC + c] * dw_w[c * 9 + (dy + 1) * 3 + (dx + 1)];
            }
        }
        float inv = rsqrtf(bn1_v[c] + 1e-5f);
        float v = (acc - bn1_m[c]) * inv * bn1_g[c] + bn1_b[c];
        row[e] = fmaxf(v, 0.f);
    }
    __syncthreads();
    for (int e = t; e < WW * CC; e += 256) {
        int w = e / CC, o = e % CC;
        float acc = pw_b[o];
        for (int c = 0; c < CC; ++c)
            acc += row[w * CC + c] * pwl[o * 97 + c];
        float inv = rsqrtf(bn2_v[o] + 1e-5f);
        float v = (acc - bn2_m[o]) * inv * bn2_g[o] + bn2_b[o];
        conv_out[((b * HH + h) * WW + w) * CC + o] = v;
    }
}

// ---------------- K2: LN + in_proj -> xm_raw (B,192,L), z (B,192,L) ----------------
__global__ __launch_bounds__(64) void k2_inproj(const float* __restrict__ x,
    const float* __restrict__ ln_g, const float* __restrict__ ln_b,
    const float* __restrict__ ipw,
    float* __restrict__ xm_raw, float* __restrict__ z_buf) {
    int t0 = blockIdx.x * 64;
    int og = blockIdx.y;       // 0..3, 96 outputs each
    int b = blockIdx.z;
    int lane = threadIdx.x;
    __shared__ float xt[64 * 97];
    const float* xb = x + (b * LL + t0) * CC;
    for (int e = lane; e < 64 * CC; e += 64) {
        int p = e / CC, c = e % CC;
        xt[p * 97 + c] = xb[e];
    }
    __syncthreads();
    float xr[96];
    float s = 0.f, s2 = 0.f;
    #pragma unroll
    for (int c = 0; c < CC; ++c) {
        float v = xt[lane * 97 + c];
        xr[c] = v; s += v; s2 += v * v;
    }
    float m = s * (1.f / 96.f);
    float var = s2 * (1.f / 96.f) - m * m;
    float inv = rsqrtf(var + 1e-5f);
    #pragma unroll
    for (int c = 0; c < CC; ++c)
        xr[c] = (xr[c] - m) * inv * ln_g[c] + ln_b[c];
    int p = t0 + lane;
    for (int o = 0; o < 96; ++o) {
        int out = og * 96 + o;
        const float* wrow = ipw + out * CC;
        float acc = 0.f;
        #pragma unroll
        for (int c = 0; c < CC; ++c) acc += xr[c] * wrow[c];
        if (out < DI) xm_raw[(b * DI + out) * LL + p] = acc;
        else          z_buf[(b * DI + (out - DI)) * LL + p] = acc;
    }
}

// ---------------- K3: dwconv3 + SiLU -> v1 (row-major), v2 (col-major) ----------------
__global__ __launch_bounds__(256) void k3_dw(const float* __restrict__ xm_raw,
    const float* __restrict__ conv_w, const float* __restrict__ conv_b,
    float* __restrict__ v1, float* __restrict__ v2) {
    int bd = blockIdx.x;            // b*192 + d
    int d = bd % DI;
    __shared__ float tile[HH * 57];
    const float* src = xm_raw + bd * LL;
    float wloc[9];
    #pragma unroll
    for (int i = 0; i < 9; ++i) wloc[i] = conv_w[d * 9 + i];
    float bias = conv_b[d];
    for (int e = threadIdx.x; e < LL; e += 256) {
        int h = e / WW, w = e % WW;
        float acc = bias;
        #pragma unroll
        for (int dy = -1; dy <= 1; ++dy) {
            int hh = h + dy; if (hh < 0 || hh >= HH) continue;
            #pragma unroll
            for (int dx = -1; dx <= 1; ++dx) {
                int ww = w + dx; if (ww < 0 || ww >= WW) continue;
                acc += src[hh * WW + ww] * wloc[(dy + 1) * 3 + (dx + 1)];
            }
        }
        float sig = 1.f / (1.f + __expf(-acc));
        float v = acc * sig;
        v1[bd * LL + e] = v;
        tile[h * 57 + w] = v;
    }
    __syncthreads();
    for (int e = threadIdx.x; e < LL; e += 256) {
        int w = e / HH, h = e % HH;      // e = colmajor index w*56+h
        v2[bd * LL + e] = tile[h * 57 + w];
    }
}

// ---------------- K4: x_proj + dt_proj + softplus -> dt_s, B_s, C_s (scan-storage order) --
__global__ __launch_bounds__(64) void k4_proj(const float* __restrict__ v1,
    const float* __restrict__ v2, const float* __restrict__ xpw,
    const float* __restrict__ dtw, const float* __restrict__ dtb,
    float* __restrict__ dt_s, float* __restrict__ B_s, float* __restrict__ C_s) {
    int lane = threadIdx.x;
    int s = blockIdx.x * 64 + lane;
    int dir = blockIdx.y;          // 0: row-major (k=0,2), 1: col-major (k=1,3)
    int b = blockIdx.z;
    const float* src = (dir == 0 ? v1 : v2) + b * DI * LL;
    int kA = dir, kB = dir + 2;
    float a0[38], a1[38];
    #pragma unroll
    for (int c = 0; c < 38; ++c) { a0[c] = 0.f; a1[c] = 0.f; }
    for (int d = 0; d < DI; ++d) {
        float xv = src[d * LL + s];
        const float* wA = xpw + (kA * 38) * DI + d;
        const float* wB = xpw + (kB * 38) * DI + d;
        #pragma unroll
        for (int c = 0; c < 38; ++c) {
            a0[c] += xv * wA[c * DI];
            a1[c] += xv * wB[c * DI];
        }
    }
    #pragma unroll
    for (int n = 0; n < NS; ++n) {
        B_s[((b * 4 + kA) * NS + n) * LL + s] = a0[6 + n];
        C_s[((b * 4 + kA) * NS + n) * LL + s] = a0[22 + n];
        B_s[((b * 4 + kB) * NS + n) * LL + s] = a1[6 + n];
        C_s[((b * 4 + kB) * NS + n) * LL + s] = a1[22 + n];
    }
    for (int d = 0; d < DI; ++d) {
        float accA = dtb[kA * DI + d], accB = dtb[kB * DI + d];
        #pragma unroll
        for (int r = 0; r < RR; ++r) {
            accA += a0[r] * dtw[(kA * DI + d) * RR + r];
            accB += a1[r] * dtw[(kB * DI + d) * RR + r];
        }
        dt_s[((b * 4 + kA) * DI + d) * LL + s] = softplusf(accA);
        dt_s[((b * 4 + kB) * DI + d) * LL + s] = softplusf(accB);
    }
}

// ---------------- K5: selective scan ----------------
// grid (48, 4, 2): one wave per (b, k, 4 d's).  lane = dl*16 + n
__global__ __launch_bounds__(64) void k5_scan(const float* __restrict__ dt_s,
    const float* __restrict__ B_s, const float* __restrict__ C_s,
    const float* __restrict__ v1, const float* __restrict__ v2,
    const float* __restrict__ A_logs, float* __restrict__ y_scan) {
    int dg = blockIdx.x, k = blockIdx.y, b = blockIdx.z;
    int d0 = dg * 4;
    int lane = threadIdx.x;
    int dl = lane >> 4, n = lane & 15;
    __shared__ float dt_l[4 * 65], u_l[4 * 65], b_l[16 * 65], c_l[16 * 65], y_l[4 * 65];
    int d = d0 + dl;
    float Av = -__expf(A_logs[(k * DI + d) * NS + n]);
    const float* dtp = dt_s + ((b * 4 + k) * DI + d0) * LL;
    const float* up = ((k == 0 || k == 2) ? v1 : v2) + (b * DI + d0) * LL;
    const float* bp = B_s + ((b * 4 + k) * NS) * LL;
    const float* cp = C_s + ((b * 4 + k) * NS) * LL;
    float* yp = y_scan + ((b * 4 + k) * DI + d0) * LL;
    bool fwd = (k < 2);
    float h = 0.f;
    for (int ci = 0; ci < NT; ++ci) {
        int s0 = fwd ? ci * 64 : (LL - (ci + 1) * 64);
        #pragma unroll
        for (int r = 0; r < 4; ++r) {
            dt_l[r * 65 + lane] = dtp[r * LL + s0 + lane];
            u_l[r * 65 + lane]  = up[r * LL + s0 + lane];
        }
        #pragma unroll
        for (int r = 0; r < 16; ++r) {
            b_l[r * 65 + lane] = bp[r * LL + s0 + lane];
            c_l[r * 65 + lane] = cp[r * LL + s0 + lane];
        }
        __syncthreads();
        #pragma unroll 4
        for (int jj = 0; jj < 64; ++jj) {
            int j = fwd ? jj : 63 - jj;
            float dtv = dt_l[dl * 65 + j];
            float uv  = u_l[dl * 65 + j];
            float bv  = b_l[n * 65 + j];
            float cv  = c_l[n * 65 + j];
            h = __expf(dtv * Av) * h + dtv * bv * uv;
            float y = h * cv;
            y += __shfl_xor(y, 1);
            y += __shfl_xor(y, 2);
            y += __shfl_xor(y, 4);
            y += __shfl_xor(y, 8);
            if (n == 0) y_l[dl * 65 + j] = y;
        }
        __syncthreads();
        #pragma unroll
        for (int r = 0; r < 4; ++r)
            yp[r * LL + s0 + lane] = y_l[r * 65 + lane];
        __syncthreads();
    }
}

// ---------------- K5b: transpose y for k=1,3 (colmajor storage -> rowmajor) ------------
__global__ __launch_bounds__(64) void k5b_tr(const float* __restrict__ y_scan,
                                             float* __restrict__ y13t) {
    int idx = blockIdx.x;          // (b*2+kk)*192 + d
    int d = idx % DI;
    int bk = idx / DI;
    int kk = bk % 2, b = bk / 2;
    int k = (kk == 0) ? 1 : 3;
    __shared__ float tile[HH * 57];
    const float* src = y_scan + ((b * 4 + k) * DI + d) * LL;
    for (int e = threadIdx.x; e < LL; e += 64) {
        int w = e / HH, h = e % HH;     // e is colmajor = w*56+h
        tile[h * 57 + w] = src[e];
    }
    __syncthreads();
    float* dst = y13t + idx * LL;
    for (int e = threadIdx.x; e < LL; e += 64) {
        int h = e / WW, w = e % WW;
        dst[e] = tile[h * 57 + w];
    }
}

// ---------------- K6: gather 4 dirs + D*u + out_norm + silu(z) gate -> t (B,192,L) -----
__global__ __launch_bounds__(256) void k6_gather(const float* __restrict__ y_scan,
    const float* __restrict__ y13t, const float* __restrict__ v1,
    const float* __restrict__ z_buf, const float* __restrict__ Ds,
    const float* __restrict__ ong, const float* __restrict__ onb,
    float* __restrict__ t_buf) {
    int t0 = blockIdx.x * 64;
    int b = blockIdx.y;
    int lane = threadIdx.x & 63, wv = threadIdx.x >> 6;
    int p = t0 + lane;
    __shared__ float yv[DI * 65];          // 49920 B
    __shared__ float ps[4][64], ps2[4][64];
    float s = 0.f, s2 = 0.f;
    for (int d = wv * 48; d < wv * 48 + 48; ++d) {
        float dsum = Ds[d] + Ds[DI + d] + Ds[2 * DI + d] + Ds[3 * DI + d];
        float val = y_scan[((b * 4 + 0) * DI + d) * LL + p]
                  + y_scan[((b * 4 + 2) * DI + d) * LL + p]
                  + y13t[((b * 2 + 0) * DI + d) * LL + p]
                  + y13t[((b * 2 + 1) * DI + d) * LL + p]
                  + v1[(b * DI + d) * LL + p] * dsum;
        yv[d * 65 + lane] = val;
        s += val; s2 += val * val;
    }
    ps[wv][lane] = s; ps2[wv][lane] = s2;
    __syncthreads();
    float st = 0.f, st2 = 0.f;
    #pragma unroll
    for (int i = 0; i < 4; ++i) { st += ps[i][lane]; st2 += ps2[i][lane]; }
    float m = st * (1.f / 192.f);
    float inv = rsqrtf(st2 * (1.f / 192.f) - m * m + 1e-5f);
    for (int d = wv * 48; d < wv * 48 + 48; ++d) {
        float val = (yv[d * 65 + lane] - m) * inv * ong[d] + onb[d];
        float zz = z_buf[(b * DI + d) * LL + p];
        float sig = 1.f / (1.f + __expf(-zz));
        t_buf[(b * DI + d) * LL + p] = val * zz * sig;
    }
}

// ---------------- K7: fused matmul (conv_out | t@W2) + fus_b + LN + residual -----------
__global__ __launch_bounds__(256) void k7_final(const float* __restrict__ t_buf,
    const float* __restrict__ conv_out, const float* __restrict__ W2,
    const float* __restrict__ fus_w, const float* __restrict__ fus_b,
    const float* __restrict__ flg, const float* __restrict__ flb,
    const float* __restrict__ x, float* __restrict__ out) {
    int t0 = blockIdx.x * 64;
    int b = blockIdx.y;
    int lane = threadIdx.x & 63, wv = threadIdx.x >> 6;
    int p = t0 + lane;
    __shared__ float ct[64 * 97];          // conv tile
    __shared__ float res[64 * 97];         // staged result
    __shared__ float ps[4][64], ps2[4][64];
    const float* cb = conv_out + (b * LL + t0) * CC;
    for (int e = threadIdx.x; e < 64 * CC; e += 256) {
        int pl = e / CC, c = e % CC;
        ct[pl * 97 + c] = cb[e];
    }
    __syncthreads();
    float acc[24];
    #pragma unroll
    for (int o = 0; o < 24; ++o) acc[o] = fus_b[wv * 24 + o];
    for (int d = 0; d < DI; ++d) {
        float tv = t_buf[(b * DI + d) * LL + p];
        const float* w2 = W2 + (wv * 24) * DI + d;
        #pragma unroll
        for (int o = 0; o < 24; ++o) acc[o] += tv * w2[o * DI];
    }
    for (int c = 0; c < CC; ++c) {
        float cv = ct[lane * 97 + c];
        const float* fw = fus_w + (wv * 24) * DI + c;
        #pragma unroll
        for (int o = 0; o < 24; ++o) acc[o] += cv * fw[o * DI];
    }
    float s = 0.f, s2 = 0.f;
    #pragma unroll
    for (int o = 0; o < 24; ++o) { s += acc[o]; s2 += acc[o] * acc[o]; }
    ps[wv][lane] = s; ps2[wv][lane] = s2;
    __syncthreads();
    float st = 0.f, st2 = 0.f;
    #pragma unroll
    for (int i = 0; i < 4; ++i) { st += ps[i][lane]; st2 += ps2[i][lane]; }
    float m = st * (1.f / 96.f);
    float inv = rsqrtf(st2 * (1.f / 96.f) - m * m + 1e-5f);
    #pragma unroll
    for (int o = 0; o < 24; ++o) {
        int oo = wv * 24 + o;
        res[lane * 97 + oo] = (acc[o] - m) * inv * flg[oo] + flb[oo];
    }
    __syncthreads();
    const float* xb = x + (b * LL + t0) * CC;
    float* ob = out + (b * LL + t0) * CC;
    for (int e = threadIdx.x; e < 64 * CC; e += 256) {
        int pl = e / CC, o = e % CC;
        ob[e] = xb[e] + res[pl * 97 + o];
    }
}

extern "C" void kernel_launch(void* const* d_in, const int* in_sizes, int n_in,
                              void* d_out, int out_size, void* d_ws, size_t ws_size,
                              hipStream_t stream) {
    const float* x        = (const float*)d_in[0];
    const float* dw_w     = (const float*)d_in[1];
    const float* dw_b     = (const float*)d_in[2];
    const float* bn1_g    = (const float*)d_in[3];
    const float* bn1_b    = (const float*)d_in[4];
    const float* bn1_m    = (const float*)d_in[5];
    const float* bn1_v    = (const float*)d_in[6];
    const float* pw_w     = (const float*)d_in[7];
    const float* pw_b     = (const float*)d_in[8];
    const float* bn2_g    = (const float*)d_in[9];
    const float* bn2_b    = (const float*)d_in[10];
    const float* bn2_m    = (const float*)d_in[11];
    const float* bn2_v    = (const float*)d_in[12];
    const float* ln_g     = (const float*)d_in[13];
    const float* ln_b     = (const float*)d_in[14];
    const float* ipw      = (const float*)d_in[15];
    const float* conv_w   = (const float*)d_in[16];
    const float* conv_b   = (const float*)d_in[17];
    const float* xpw      = (const float*)d_in[18];
    const float* dtw      = (const float*)d_in[19];
    const float* dtb      = (const float*)d_in[20];
    const float* A_logs   = (const float*)d_in[21];
    const float* Ds       = (const float*)d_in[22];
    const float* ong      = (const float*)d_in[23];
    const float* onb      = (const float*)d_in[24];
    const float* opw      = (const float*)d_in[25];
    const float* fus_w    = (const float*)d_in[26];
    const float* fus_b    = (const float*)d_in[27];
    const float* flg      = (const float*)d_in[28];
    const float* flb      = (const float*)d_in[29];

    float* ws = (float*)d_ws;
    float* conv_out = ws + OFF_CONV;
    float* xm_raw   = ws + OFF_XMRAW;
    float* z_buf    = ws + OFF_Z;
    float* v1       = ws + OFF_V1;
    float* v2       = ws + OFF_V2;
    float* dt_s     = ws + OFF_DT;
    float* B_s      = ws + OFF_BS;
    float* C_s      = ws + OFF_CS;
    float* y_scan   = ws + OFF_Y;
    float* y13t     = ws + OFF_Y13;
    float* t_buf    = ws + OFF_T;
    float* W2       = ws + OFF_W2;
    float* out      = (float*)d_out;

    k0_w2<<<dim3((CC * DI + 63) / 64), dim3(64), 0, stream>>>(fus_w, opw, W2);
    k1_conv<<<dim3(BZ * HH), dim3(256), 0, stream>>>(x, dw_w, dw_b, bn1_g, bn1_b, bn1_m, bn1_v,
                                                     pw_w, pw_b, bn2_g, bn2_b, bn2_m, bn2_v, conv_out);
    k2_inproj<<<dim3(NT, 4, BZ), dim3(64), 0, stream>>>(x, ln_g, ln_b, ipw, xm_raw, z_buf);
    k3_dw<<<dim3(BZ * DI), dim3(256), 0, stream>>>(xm_raw, conv_w, conv_b, v1, v2);
    k4_proj<<<dim3(NT, 2, BZ), dim3(64), 0, stream>>>(v1, v2, xpw, dtw, dtb, dt_s, B_s, C_s);
    k5_scan<<<dim3(48, 4, BZ), dim3(64), 0, stream>>>(dt_s, B_s, C_s, v1, v2, A_logs, y_scan);
    k5b_tr<<<dim3(BZ * 2 * DI), dim3(64), 0, stream>>>(y_scan, y13t);
    k6_gather<<<dim3(NT, BZ), dim3(256), 0, stream>>>(y_scan, y13t, v1, z_buf, Ds, ong, onb, t_buf);
    k7_final<<<dim3(NT, BZ), dim3(256), 0, stream>>>(t_buf, conv_out, W2, fus_w, fus_b, flg, flb, x, out);
}

// Round 2
// 833.848 us; speedup vs baseline: 1.5677x; 1.5677x over previous
//
#include <hip/hip_runtime.h>
#include <math.h>

// Problem constants
#define BZ 2
#define HH 56
#define WW 56
#define LL 3136      // 56*56
#define CC 96        // DIM
#define DI 192       // DINNER
#define NS 16        // DSTATE
#define RR 6         // DTRANK
#define NT 49        // LL/64
#define NC 49        // chunks for scan

// Workspace layout (floats) -- same footprint as round 1 (78 MB), with aliasing:
//   cumdt  -> written in-place into dt_s by phase 1
//   hlast  -> xm_raw region (free after k3)
//   H_in   -> t_buf region (free until k6)
//   xpwT   -> y13t region (free until k5b)
#define OFF_CONV   0
#define OFF_XMRAW  602112
#define OFF_Z      1806336
#define OFF_V1     3010560
#define OFF_V2     4214784
#define OFF_DT     5419008
#define OFF_BS     10235904
#define OFF_CS     10637312
#define OFF_Y      11038720
#define OFF_Y13    15855616
#define OFF_T      18264064
#define OFF_W2     19468288
// total 19486720 floats = ~78 MB

__device__ __forceinline__ float softplusf(float x) {
    if (x > 20.f) return x;
    return log1pf(__expf(x));
}

// ---------------- K0: W2[o][d] = sum_j fus_w[o][96+j] * out_proj_w[j][d] ----------------
__global__ __launch_bounds__(64) void k0_w2(const float* __restrict__ fus_w,
                                            const float* __restrict__ opw,
                                            float* __restrict__ W2) {
    int i = blockIdx.x * 64 + threadIdx.x;   // 96*192 = 18432
    if (i >= CC * DI) return;
    int o = i / DI, d = i % DI;
    float acc = 0.f;
    for (int j = 0; j < CC; ++j)
        acc += fus_w[o * DI + CC + j] * opw[j * DI + d];
    W2[i] = acc;
}

// ---------------- K0b: xpwT[k][d][c] = xpw[k][c][d] ----------------
__global__ __launch_bounds__(256) void k0b_xpwt(const float* __restrict__ xpw,
                                                float* __restrict__ xpwT) {
    int i = blockIdx.x * 256 + threadIdx.x;  // 4*192*38 = 29184
    if (i >= 4 * DI * 38) return;
    int c = i % 38;
    int kd = i / 38;
    int d = kd % DI, k = kd / DI;
    xpwT[i] = xpw[(k * 38 + c) * DI + d];
}

// ---------------- K1: conv path -> conv_out (B,L,96) NHWC ----------------
__global__ __launch_bounds__(256) void k1_conv(const float* __restrict__ x,
    const float* __restrict__ dw_w, const float* __restrict__ dw_b,
    const float* __restrict__ bn1_g, const float* __restrict__ bn1_b,
    const float* __restrict__ bn1_m, const float* __restrict__ bn1_v,
    const float* __restrict__ pw_w, const float* __restrict__ pw_b,
    const float* __restrict__ bn2_g, const float* __restrict__ bn2_b,
    const float* __restrict__ bn2_m, const float* __restrict__ bn2_v,
    float* __restrict__ conv_out) {
    int bh = blockIdx.x;
    int b = bh / HH, h = bh % HH;
    __shared__ float row[WW * CC];
    __shared__ float pwl[CC * 97];
    int t = threadIdx.x;
    for (int e = t; e < CC * CC; e += 256) {
        int o = e / CC, c = e % CC;
        pwl[o * 97 + c] = pw_w[e];
    }
    for (int e = t; e < WW * CC; e += 256) {
        int w = e / CC, c = e % CC;
        float acc = dw_b[c];
        #pragma unroll
        for (int dy = -1; dy <= 1; ++dy) {
            int hh = h + dy; if (hh < 0 || hh >= HH) continue;
            #pragma unroll
            for (int dx = -1; dx <= 1; ++dx) {
                int ww = w + dx; if (ww < 0 || ww >= WW) continue;
                acc += x[((b * HH + hh) * WW + ww) * CC + c] * dw_w[c * 9 + (dy + 1) * 3 + (dx + 1)];
            }
        }
        float inv = rsqrtf(bn1_v[c] + 1e-5f);
        float v = (acc - bn1_m[c]) * inv * bn1_g[c] + bn1_b[c];
        row[e] = fmaxf(v, 0.f);
    }
    __syncthreads();
    for (int e = t; e < WW * CC; e += 256) {
        int w = e / CC, o = e % CC;
        float acc = pw_b[o];
        for (int c = 0; c < CC; ++c)
            acc += row[w * CC + c] * pwl[o * 97 + c];
        float inv = rsqrtf(bn2_v[o] + 1e-5f);
        float v = (acc - bn2_m[o]) * inv * bn2_g[o] + bn2_b[o];
        conv_out[((b * HH + h) * WW + w) * CC + o] = v;
    }
}

// ---------------- K2: LN + in_proj -> xm_raw (B,192,L), z (B,192,L) ----------------
__global__ __launch_bounds__(64) void k2_inproj(const float* __restrict__ x,
    const float* __restrict__ ln_g, const float* __restrict__ ln_b,
    const float* __restrict__ ipw,
    float* __restrict__ xm_raw, float* __restrict__ z_buf) {
    int t0 = blockIdx.x * 64;
    int og = blockIdx.y;       // 0..3, 96 outputs each
    int b = blockIdx.z;
    int lane = threadIdx.x;
    __shared__ float xt[64 * 97];
    const float* xb = x + (b * LL + t0) * CC;
    for (int e = lane; e < 64 * CC; e += 64) {
        int p = e / CC, c = e % CC;
        xt[p * 97 + c] = xb[e];
    }
    __syncthreads();
    float xr[96];
    float s = 0.f, s2 = 0.f;
    #pragma unroll
    for (int c = 0; c < CC; ++c) {
        float v = xt[lane * 97 + c];
        xr[c] = v; s += v; s2 += v * v;
    }
    float m = s * (1.f / 96.f);
    float var = s2 * (1.f / 96.f) - m * m;
    float inv = rsqrtf(var + 1e-5f);
    #pragma unroll
    for (int c = 0; c < CC; ++c)
        xr[c] = (xr[c] - m) * inv * ln_g[c] + ln_b[c];
    int p = t0 + lane;
    for (int o = 0; o < 96; ++o) {
        int out = og * 96 + o;
        const float* wrow = ipw + out * CC;
        float acc = 0.f;
        #pragma unroll
        for (int c = 0; c < CC; ++c) acc += xr[c] * wrow[c];
        if (out < DI) xm_raw[(b * DI + out) * LL + p] = acc;
        else          z_buf[(b * DI + (out - DI)) * LL + p] = acc;
    }
}

// ---------------- K3: dwconv3 + SiLU -> v1 (row-major), v2 (col-major) ----------------
__global__ __launch_bounds__(256) void k3_dw(const float* __restrict__ xm_raw,
    const float* __restrict__ conv_w, const float* __restrict__ conv_b,
    float* __restrict__ v1, float* __restrict__ v2) {
    int bd = blockIdx.x;            // b*192 + d
    int d = bd % DI;
    __shared__ float tile[HH * 57];
    const float* src = xm_raw + bd * LL;
    float wloc[9];
    #pragma unroll
    for (int i = 0; i < 9; ++i) wloc[i] = conv_w[d * 9 + i];
    float bias = conv_b[d];
    for (int e = threadIdx.x; e < LL; e += 256) {
        int h = e / WW, w = e % WW;
        float acc = bias;
        #pragma unroll
        for (int dy = -1; dy <= 1; ++dy) {
            int hh = h + dy; if (hh < 0 || hh >= HH) continue;
            #pragma unroll
            for (int dx = -1; dx <= 1; ++dx) {
                int ww = w + dx; if (ww < 0 || ww >= WW) continue;
                acc += src[hh * WW + ww] * wloc[(dy + 1) * 3 + (dx + 1)];
            }
        }
        float sig = 1.f / (1.f + __expf(-acc));
        float v = acc * sig;
        v1[bd * LL + e] = v;
        tile[h * 57 + w] = v;
    }
    __syncthreads();
    for (int e = threadIdx.x; e < LL; e += 256) {
        int w = e / HH, h = e % HH;      // e = colmajor index w*56+h
        v2[bd * LL + e] = tile[h * 57 + w];
    }
}

// ---------------- K4: x_proj + dt_proj + softplus -> dt_s, B_s, C_s ----------------
__global__ __launch_bounds__(64) void k4_proj(const float* __restrict__ v1,
    const float* __restrict__ v2, const float* __restrict__ xpwT,
    const float* __restrict__ dtw, const float* __restrict__ dtb,
    float* __restrict__ dt_s, float* __restrict__ B_s, float* __restrict__ C_s) {
    int lane = threadIdx.x;
    int s = blockIdx.x * 64 + lane;
    int dir = blockIdx.y;          // 0: row-major (k=0,2), 1: col-major (k=1,3)
    int b = blockIdx.z;
    const float* src = (dir == 0 ? v1 : v2) + b * DI * LL;
    int kA = dir, kB = dir + 2;
    float a0[38], a1[38];
    #pragma unroll
    for (int c = 0; c < 38; ++c) { a0[c] = 0.f; a1[c] = 0.f; }
    for (int d = 0; d < DI; ++d) {
        float xv = src[d * LL + s];
        const float* wA = xpwT + (kA * DI + d) * 38;   // contiguous, wave-uniform
        const float* wB = xpwT + (kB * DI + d) * 38;
        #pragma unroll
        for (int c = 0; c < 38; ++c) {
            a0[c] += xv * wA[c];
            a1[c] += xv * wB[c];
        }
    }
    #pragma unroll
    for (int n = 0; n < NS; ++n) {
        B_s[((b * 4 + kA) * NS + n) * LL + s] = a0[6 + n];
        C_s[((b * 4 + kA) * NS + n) * LL + s] = a0[22 + n];
        B_s[((b * 4 + kB) * NS + n) * LL + s] = a1[6 + n];
        C_s[((b * 4 + kB) * NS + n) * LL + s] = a1[22 + n];
    }
    for (int d = 0; d < DI; ++d) {
        float accA = dtb[kA * DI + d], accB = dtb[kB * DI + d];
        #pragma unroll
        for (int r = 0; r < RR; ++r) {
            accA += a0[r] * dtw[(kA * DI + d) * RR + r];
            accB += a1[r] * dtw[(kB * DI + d) * RR + r];
        }
        dt_s[((b * 4 + kA) * DI + d) * LL + s] = softplusf(accA);
        dt_s[((b * 4 + kB) * DI + d) * LL + s] = softplusf(accB);
    }
}

// ---------------- K5a: scan phase 1 — per-chunk local scan ----------------
// grid (48*NC, 4, 2), one wave per (b,k,4d,chunk). lane = dl*16 + n.
// Writes: y_scan = local y; dt_s overwritten in-place with within-chunk inclusive
// cumulative dt; hlast[bk][c][d*16+n] = local state at chunk end.
__global__ __launch_bounds__(64) void k5a_scan(float* __restrict__ dt_s,
    const float* __restrict__ B_s, const float* __restrict__ C_s,
    const float* __restrict__ v1, const float* __restrict__ v2,
    const float* __restrict__ A_logs, float* __restrict__ y_scan,
    float* __restrict__ hlast) {
    int bx = blockIdx.x;
    int dg = bx % 48, c = bx / 48;
    int k = blockIdx.y, b = blockIdx.z;
    int d0 = dg * 4;
    int lane = threadIdx.x;
    int dl = lane >> 4, n = lane & 15;
    __shared__ float dt_l[4 * 65], u_l[4 * 65], b_l[16 * 65], c_l[16 * 65];
    __shared__ float y_l[4 * 65], cd_l[4 * 65];
    int d = d0 + dl;
    int bk = b * 4 + k;
    float Av = -__expf(A_logs[(k * DI + d) * NS + n]);
    bool fwd = (k < 2);
    int s0 = fwd ? c * 64 : (LL - (c + 1) * 64);
    const float* dtp = dt_s + (bk * DI + d0) * LL;
    const float* up = ((k == 0 || k == 2) ? v1 : v2) + (b * DI + d0) * LL;
    const float* bp = B_s + (bk * NS) * LL;
    const float* cp = C_s + (bk * NS) * LL;
    float* yp = y_scan + (bk * DI + d0) * LL;
    #pragma unroll
    for (int r = 0; r < 4; ++r) {
        dt_l[r * 65 + lane] = dtp[r * LL + s0 + lane];
        u_l[r * 65 + lane]  = up[r * LL + s0 + lane];
    }
    #pragma unroll
    for (int r = 0; r < 16; ++r) {
        b_l[r * 65 + lane] = bp[r * LL + s0 + lane];
        c_l[r * 65 + lane] = cp[r * LL + s0 + lane];
    }
    __syncthreads();
    float h = 0.f, run = 0.f;
    #pragma unroll 4
    for (int jj = 0; jj < 64; ++jj) {
        int j = fwd ? jj : 63 - jj;
        float dtv = dt_l[dl * 65 + j];
        float uv  = u_l[dl * 65 + j];
        float bv  = b_l[n * 65 + j];
        float cv  = c_l[n * 65 + j];
        run += dtv;
        h = __expf(dtv * Av) * h + dtv * bv * uv;
        float y = h * cv;
        y += __shfl_xor(y, 1);
        y += __shfl_xor(y, 2);
        y += __shfl_xor(y, 4);
        y += __shfl_xor(y, 8);
        if (n == 0) { y_l[dl * 65 + j] = y; cd_l[dl * 65 + j] = run; }
    }
    __syncthreads();
    #pragma unroll
    for (int r = 0; r < 4; ++r) {
        yp[r * LL + s0 + lane] = y_l[r * 65 + lane];
        dt_s[(bk * DI + d0 + r) * LL + s0 + lane] = cd_l[r * 65 + lane];  // cumdt in-place
    }
    hlast[(bk * NC + c) * (48 * 64) + dg * 64 + lane] = h;
}

// ---------------- K5c: scan phase 2 — serial chunk combine ----------------
// grid (48, 4, 2), one wave. H_in[c] = state entering chunk c.
__global__ __launch_bounds__(64) void k5c_comb(const float* __restrict__ hlast,
    const float* __restrict__ cumdt, const float* __restrict__ A_logs,
    float* __restrict__ hin) {
    int dg = blockIdx.x, k = blockIdx.y, b = blockIdx.z;
    int lane = threadIdx.x, dl = lane >> 4, n = lane & 15;
    int d = dg * 4 + dl;
    int bk = b * 4 + k;
    bool fwd = (k < 2);
    float Av = -__expf(A_logs[(k * DI + d) * NS + n]);
    float H = 0.f;
    for (int c = 0; c < NC; ++c) {
        hin[(bk * NC + c) * (48 * 64) + dg * 64 + lane] = H;
        int s0 = fwd ? c * 64 : (LL - (c + 1) * 64);
        int jlast = fwd ? s0 + 63 : s0;                 // last processed position in chunk
        float T = cumdt[(bk * DI + d) * LL + jlast];    // total dt of chunk
        float hl = hlast[(bk * NC + c) * (48 * 64) + dg * 64 + lane];
        H = hl + __expf(Av * T) * H;
    }
}

// ---------------- K5d: scan phase 3 — parallel correction ----------------
// y[s] += sum_n C[n][s] * exp(A[n]*cumdt[s]) * H_in[chunk(s)][n]
// grid (48, 4, 2) x 256.  Skips the chunk with H_in = 0.
__global__ __launch_bounds__(256) void k5d_corr(const float* __restrict__ cumdt,
    const float* __restrict__ C_s, const float* __restrict__ hin,
    const float* __restrict__ A_logs, float* __restrict__ y_scan) {
    int t = blockIdx.x;
    int k = blockIdx.y, b = blockIdx.z;
    bool fwd = (k < 2);
    int tile = fwd ? (t + 1) : t;        // spatial tile needing correction
    int c = fwd ? tile : (48 - tile);    // chunk index covering that tile
    int s0 = tile * 64;
    int lane = threadIdx.x & 63, wv = threadIdx.x >> 6;
    int bk = b * 4 + k;
    __shared__ float c_l[16 * 65];
    for (int e = threadIdx.x; e < 16 * 64; e += 256) {
        int n = e >> 6, s = e & 63;
        c_l[n * 65 + s] = C_s[(bk * NS + n) * LL + s0 + s];
    }
    __syncthreads();
    for (int dd = 0; dd < 48; ++dd) {
        int d = wv * 48 + dd;
        float cd = cumdt[(bk * DI + d) * LL + s0 + lane];
        const float* hp = hin + (bk * NC + c) * (48 * 64) + d * 16;
        const float* ap = A_logs + (k * DI + d) * NS;
        float acc = 0.f;
        #pragma unroll
        for (int n = 0; n < 16; ++n) {
            float Av = -__expf(ap[n]);
            acc += c_l[n * 65 + lane] * __expf(Av * cd) * hp[n];
        }
        y_scan[(bk * DI + d) * LL + s0 + lane] += acc;
    }
}

// ---------------- K5b: transpose y for k=1,3 (colmajor storage -> rowmajor) ------------
__global__ __launch_bounds__(64) void k5b_tr(const float* __restrict__ y_scan,
                                             float* __restrict__ y13t) {
    int idx = blockIdx.x;          // (b*2+kk)*192 + d
    int d = idx % DI;
    int bk = idx / DI;
    int kk = bk % 2, b = bk / 2;
    int k = (kk == 0) ? 1 : 3;
    __shared__ float tile[HH * 57];
    const float* src = y_scan + ((b * 4 + k) * DI + d) * LL;
    for (int e = threadIdx.x; e < LL; e += 64) {
        int w = e / HH, h = e % HH;
        tile[h * 57 + w] = src[e];
    }
    __syncthreads();
    float* dst = y13t + idx * LL;
    for (int e = threadIdx.x; e < LL; e += 64) {
        int h = e / WW, w = e % WW;
        dst[e] = tile[h * 57 + w];
    }
}

// ---------------- K6: gather 4 dirs + D*u + out_norm + silu(z) gate -> t (B,192,L) -----
__global__ __launch_bounds__(256) void k6_gather(const float* __restrict__ y_scan,
    const float* __restrict__ y13t, const float* __restrict__ v1,
    const float* __restrict__ z_buf, const float* __restrict__ Ds,
    const float* __restrict__ ong, const float* __restrict__ onb,
    float* __restrict__ t_buf) {
    int t0 = blockIdx.x * 64;
    int b = blockIdx.y;
    int lane = threadIdx.x & 63, wv = threadIdx.x >> 6;
    int p = t0 + lane;
    __shared__ float yv[DI * 65];
    __shared__ float ps[4][64], ps2[4][64];
    float s = 0.f, s2 = 0.f;
    for (int d = wv * 48; d < wv * 48 + 48; ++d) {
        float dsum = Ds[d] + Ds[DI + d] + Ds[2 * DI + d] + Ds[3 * DI + d];
        float val = y_scan[((b * 4 + 0) * DI + d) * LL + p]
                  + y_scan[((b * 4 + 2) * DI + d) * LL + p]
                  + y13t[((b * 2 + 0) * DI + d) * LL + p]
                  + y13t[((b * 2 + 1) * DI + d) * LL + p]
                  + v1[(b * DI + d) * LL + p] * dsum;
        yv[d * 65 + lane] = val;
        s += val; s2 += val * val;
    }
    ps[wv][lane] = s; ps2[wv][lane] = s2;
    __syncthreads();
    float st = 0.f, st2 = 0.f;
    #pragma unroll
    for (int i = 0; i < 4; ++i) { st += ps[i][lane]; st2 += ps2[i][lane]; }
    float m = st * (1.f / 192.f);
    float inv = rsqrtf(st2 * (1.f / 192.f) - m * m + 1e-5f);
    for (int d = wv * 48; d < wv * 48 + 48; ++d) {
        float val = (yv[d * 65 + lane] - m) * inv * ong[d] + onb[d];
        float zz = z_buf[(b * DI + d) * LL + p];
        float sig = 1.f / (1.f + __expf(-zz));
        t_buf[(b * DI + d) * LL + p] = val * zz * sig;
    }
}

// ---------------- K7: fused matmul (conv_out | t@W2) + fus_b + LN + residual -----------
__global__ __launch_bounds__(256) void k7_final(const float* __restrict__ t_buf,
    const float* __restrict__ conv_out, const float* __restrict__ W2,
    const float* __restrict__ fus_w, const float* __restrict__ fus_b,
    const float* __restrict__ flg, const float* __restrict__ flb,
    const float* __restrict__ x, float* __restrict__ out) {
    int t0 = blockIdx.x * 64;
    int b = blockIdx.y;
    int lane = threadIdx.x & 63, wv = threadIdx.x >> 6;
    int p = t0 + lane;
    __shared__ float ct[64 * 97];
    __shared__ float res[64 * 97];
    __shared__ float ps[4][64], ps2[4][64];
    const float* cb = conv_out + (b * LL + t0) * CC;
    for (int e = threadIdx.x; e < 64 * CC; e += 256) {
        int pl = e / CC, c = e % CC;
        ct[pl * 97 + c] = cb[e];
    }
    __syncthreads();
    float acc[24];
    #pragma unroll
    for (int o = 0; o < 24; ++o) acc[o] = fus_b[wv * 24 + o];
    for (int d = 0; d < DI; ++d) {
        float tv = t_buf[(b * DI + d) * LL + p];
        const float* w2 = W2 + (wv * 24) * DI + d;
        #pragma unroll
        for (int o = 0; o < 24; ++o) acc[o] += tv * w2[o * DI];
    }
    for (int c = 0; c < CC; ++c) {
        float cv = ct[lane * 97 + c];
        const float* fw = fus_w + (wv * 24) * DI + c;
        #pragma unroll
        for (int o = 0; o < 24; ++o) acc[o] += cv * fw[o * DI];
    }
    float s = 0.f, s2 = 0.f;
    #pragma unroll
    for (int o = 0; o < 24; ++o) { s += acc[o]; s2 += acc[o] * acc[o]; }
    ps[wv][lane] = s; ps2[wv][lane] = s2;
    __syncthreads();
    float st = 0.f, st2 = 0.f;
    #pragma unroll
    for (int i = 0; i < 4; ++i) { st += ps[i][lane]; st2 += ps2[i][lane]; }
    float m = st * (1.f / 96.f);
    float inv = rsqrtf(st2 * (1.f / 96.f) - m * m + 1e-5f);
    #pragma unroll
    for (int o = 0; o < 24; ++o) {
        int oo = wv * 24 + o;
        res[lane * 97 + oo] = (acc[o] - m) * inv * flg[oo] + flb[oo];
    }
    __syncthreads();
    const float* xb = x + (b * LL + t0) * CC;
    float* ob = out + (b * LL + t0) * CC;
    for (int e = threadIdx.x; e < 64 * CC; e += 256) {
        int pl = e / CC, o = e % CC;
        ob[e] = xb[e] + res[pl * 97 + o];
    }
}

extern "C" void kernel_launch(void* const* d_in, const int* in_sizes, int n_in,
                              void* d_out, int out_size, void* d_ws, size_t ws_size,
                              hipStream_t stream) {
    const float* x        = (const float*)d_in[0];
    const float* dw_w     = (const float*)d_in[1];
    const float* dw_b     = (const float*)d_in[2];
    const float* bn1_g    = (const float*)d_in[3];
    const float* bn1_b    = (const float*)d_in[4];
    const float* bn1_m    = (const float*)d_in[5];
    const float* bn1_v    = (const float*)d_in[6];
    const float* pw_w     = (const float*)d_in[7];
    const float* pw_b     = (const float*)d_in[8];
    const float* bn2_g    = (const float*)d_in[9];
    const float* bn2_b    = (const float*)d_in[10];
    const float* bn2_m    = (const float*)d_in[11];
    const float* bn2_v    = (const float*)d_in[12];
    const float* ln_g     = (const float*)d_in[13];
    const float* ln_b     = (const float*)d_in[14];
    const float* ipw      = (const float*)d_in[15];
    const float* conv_w   = (const float*)d_in[16];
    const float* conv_b   = (const float*)d_in[17];
    const float* xpw      = (const float*)d_in[18];
    const float* dtw      = (const float*)d_in[19];
    const float* dtb      = (const float*)d_in[20];
    const float* A_logs   = (const float*)d_in[21];
    const float* Ds       = (const float*)d_in[22];
    const float* ong      = (const float*)d_in[23];
    const float* onb      = (const float*)d_in[24];
    const float* opw      = (const float*)d_in[25];
    const float* fus_w    = (const float*)d_in[26];
    const float* fus_b    = (const float*)d_in[27];
    const float* flg      = (const float*)d_in[28];
    const float* flb      = (const float*)d_in[29];

    float* ws = (float*)d_ws;
    float* conv_out = ws + OFF_CONV;
    float* xm_raw   = ws + OFF_XMRAW;
    float* z_buf    = ws + OFF_Z;
    float* v1       = ws + OFF_V1;
    float* v2       = ws + OFF_V2;
    float* dt_s     = ws + OFF_DT;     // becomes cumdt after k5a (in place)
    float* B_s      = ws + OFF_BS;
    float* C_s      = ws + OFF_CS;
    float* y_scan   = ws + OFF_Y;
    float* y13t     = ws + OFF_Y13;
    float* t_buf    = ws + OFF_T;
    float* W2       = ws + OFF_W2;
    float* hlast    = xm_raw;          // alias: xm_raw dead after k3
    float* hin      = t_buf;           // alias: t_buf dead until k6
    float* xpwT     = y13t;            // alias: y13t dead until k5b
    float* out      = (float*)d_out;

    k0_w2<<<dim3((CC * DI + 63) / 64), dim3(64), 0, stream>>>(fus_w, opw, W2);
    k0b_xpwt<<<dim3((4 * DI * 38 + 255) / 256), dim3(256), 0, stream>>>(xpw, xpwT);
    k1_conv<<<dim3(BZ * HH), dim3(256), 0, stream>>>(x, dw_w, dw_b, bn1_g, bn1_b, bn1_m, bn1_v,
                                                     pw_w, pw_b, bn2_g, bn2_b, bn2_m, bn2_v, conv_out);
    k2_inproj<<<dim3(NT, 4, BZ), dim3(64), 0, stream>>>(x, ln_g, ln_b, ipw, xm_raw, z_buf);
    k3_dw<<<dim3(BZ * DI), dim3(256), 0, stream>>>(xm_raw, conv_w, conv_b, v1, v2);
    k4_proj<<<dim3(NT, 2, BZ), dim3(64), 0, stream>>>(v1, v2, xpwT, dtw, dtb, dt_s, B_s, C_s);
    k5a_scan<<<dim3(48 * NC, 4, BZ), dim3(64), 0, stream>>>(dt_s, B_s, C_s, v1, v2, A_logs, y_scan, hlast);
    k5c_comb<<<dim3(48, 4, BZ), dim3(64), 0, stream>>>(hlast, dt_s, A_logs, hin);
    k5d_corr<<<dim3(48, 4, BZ), dim3(256), 0, stream>>>(dt_s, C_s, hin, A_logs, y_scan);
    k5b_tr<<<dim3(BZ * 2 * DI), dim3(64), 0, stream>>>(y_scan, y13t);
    k6_gather<<<dim3(NT, BZ), dim3(256), 0, stream>>>(y_scan, y13t, v1, z_buf, Ds, ong, onb, t_buf);
    k7_final<<<dim3(NT, BZ), dim3(256), 0, stream>>>(t_buf, conv_out, W2, fus_w, fus_b, flg, flb, x, out);
}

// Round 3
// 635.658 us; speedup vs baseline: 2.0564x; 1.3118x over previous
//
#include <hip/hip_runtime.h>
#include <math.h>

// Problem constants
#define BZ 2
#define HH 56
#define WW 56
#define LL 3136      // 56*56
#define CC 96        // DIM
#define DI 192       // DINNER
#define NS 16        // DSTATE
#define RR 6         // DTRANK
#define NT 49        // LL/64
#define NC 49        // chunks for scan

// Workspace layout (floats)
#define OFF_CONV   0
#define OFF_XMRAW  602112
#define OFF_Z      1806336
#define OFF_V1     3010560
#define OFF_V2     4214784
#define OFF_DT     5419008
#define OFF_BS     10235904
#define OFF_CS     10637312
#define OFF_Y      11038720
#define OFF_Y13    15855616
#define OFF_T      18264064
#define OFF_W2     19468288
// total 19486720 floats = ~78 MB

__device__ __forceinline__ float softplusf(float x) {
    if (x > 20.f) return x;
    return log1pf(__expf(x));
}

// ---------------- K0: W2[o][d] = sum_j fus_w[o][96+j] * out_proj_w[j][d] ----------------
__global__ __launch_bounds__(64) void k0_w2(const float* __restrict__ fus_w,
                                            const float* __restrict__ opw,
                                            float* __restrict__ W2) {
    int i = blockIdx.x * 64 + threadIdx.x;
    if (i >= CC * DI) return;
    int o = i / DI, d = i % DI;
    float acc = 0.f;
    for (int j = 0; j < CC; ++j)
        acc += fus_w[o * DI + CC + j] * opw[j * DI + d];
    W2[i] = acc;
}

// ---------------- K1: conv path -> conv_out (B,L,96) NHWC ----------------
__global__ __launch_bounds__(256) void k1_conv(const float* __restrict__ x,
    const float* __restrict__ dw_w, const float* __restrict__ dw_b,
    const float* __restrict__ bn1_g, const float* __restrict__ bn1_b,
    const float* __restrict__ bn1_m, const float* __restrict__ bn1_v,
    const float* __restrict__ pw_w, const float* __restrict__ pw_b,
    const float* __restrict__ bn2_g, const float* __restrict__ bn2_b,
    const float* __restrict__ bn2_m, const float* __restrict__ bn2_v,
    float* __restrict__ conv_out) {
    int bh = blockIdx.x;
    int b = bh / HH, h = bh % HH;
    __shared__ float row[WW * CC];
    __shared__ float pwl[CC * 97];
    int t = threadIdx.x;
    for (int e = t; e < CC * CC; e += 256) {
        int o = e / CC, c = e % CC;
        pwl[o * 97 + c] = pw_w[e];
    }
    for (int e = t; e < WW * CC; e += 256) {
        int w = e / CC, c = e % CC;
        float acc = dw_b[c];
        #pragma unroll
        for (int dy = -1; dy <= 1; ++dy) {
            int hh = h + dy; if (hh < 0 || hh >= HH) continue;
            #pragma unroll
            for (int dx = -1; dx <= 1; ++dx) {
                int ww = w + dx; if (ww < 0 || ww >= WW) continue;
                acc += x[((b * HH + hh) * WW + ww) * CC + c] * dw_w[c * 9 + (dy + 1) * 3 + (dx + 1)];
            }
        }
        float inv = rsqrtf(bn1_v[c] + 1e-5f);
        float v = (acc - bn1_m[c]) * inv * bn1_g[c] + bn1_b[c];
        row[e] = fmaxf(v, 0.f);
    }
    __syncthreads();
    for (int e = t; e < WW * CC; e += 256) {
        int w = e / CC, o = e % CC;
        float acc = pw_b[o];
        for (int c = 0; c < CC; ++c)
            acc += row[w * CC + c] * pwl[o * 97 + c];
        float inv = rsqrtf(bn2_v[o] + 1e-5f);
        float v = (acc - bn2_m[o]) * inv * bn2_g[o] + bn2_b[o];
        conv_out[((b * HH + h) * WW + w) * CC + o] = v;
    }
}

// ---------------- K2: LN + in_proj (tiled) -> xm_raw (B,192,L), z (B,192,L) -------------
// grid (NT, 4, BZ) x 256.  Block: 64 positions x 96 outputs (group og).
__global__ __launch_bounds__(256) void k2_inproj(const float* __restrict__ x,
    const float* __restrict__ ln_g, const float* __restrict__ ln_b,
    const float* __restrict__ ipw,
    float* __restrict__ xm_raw, float* __restrict__ z_buf) {
    int t0 = blockIdx.x * 64;
    int og = blockIdx.y;
    int b = blockIdx.z;
    int lane = threadIdx.x & 63, wv = threadIdx.x >> 6;
    __shared__ float xt[64 * 97];      // [p][c]
    __shared__ float xn[96 * 65];      // [c][p] normalized
    __shared__ float ps[4][64], ps2[4][64];
    const float* xb = x + (b * LL + t0) * CC;
    for (int e = threadIdx.x; e < 64 * CC; e += 256) {
        int p = e / CC, c = e % CC;
        xt[p * 97 + c] = xb[e];
    }
    __syncthreads();
    // LN partial sums: thread = (wv channel-slice, lane position)
    float s = 0.f, s2 = 0.f;
    #pragma unroll
    for (int j = 0; j < 24; ++j) {
        float v = xt[lane * 97 + wv * 24 + j];
        s += v; s2 += v * v;
    }
    ps[wv][lane] = s; ps2[wv][lane] = s2;
    __syncthreads();
    float st = 0.f, st2 = 0.f;
    #pragma unroll
    for (int i = 0; i < 4; ++i) { st += ps[i][lane]; st2 += ps2[i][lane]; }
    float m = st * (1.f / 96.f);
    float inv = rsqrtf(st2 * (1.f / 96.f) - m * m + 1e-5f);
    #pragma unroll
    for (int j = 0; j < 24; ++j) {
        int c = wv * 24 + j;
        xn[c * 65 + lane] = (xt[lane * 97 + c] - m) * inv * ln_g[c] + ln_b[c];
    }
    __syncthreads();
    // Compute 24 outputs per thread: o = og*96 + wv*24 + j, position = lane
    float acc[24];
    #pragma unroll
    for (int j = 0; j < 24; ++j) acc[j] = 0.f;
    const float* wbase = ipw + (og * 96 + wv * 24) * CC;
    for (int c = 0; c < CC; ++c) {
        float xv = xn[c * 65 + lane];
        #pragma unroll
        for (int j = 0; j < 24; ++j)
            acc[j] += xv * wbase[j * CC + c];
    }
    int p = t0 + lane;
    #pragma unroll
    for (int j = 0; j < 24; ++j) {
        int out = og * 96 + wv * 24 + j;
        if (out < DI) xm_raw[(b * DI + out) * LL + p] = acc[j];
        else          z_buf[(b * DI + (out - DI)) * LL + p] = acc[j];
    }
}

// ---------------- K3: dwconv3 + SiLU -> v1 (row-major), v2 (col-major) ----------------
__global__ __launch_bounds__(256) void k3_dw(const float* __restrict__ xm_raw,
    const float* __restrict__ conv_w, const float* __restrict__ conv_b,
    float* __restrict__ v1, float* __restrict__ v2) {
    int bd = blockIdx.x;
    int d = bd % DI;
    __shared__ float tile[HH * 57];
    const float* src = xm_raw + bd * LL;
    float wloc[9];
    #pragma unroll
    for (int i = 0; i < 9; ++i) wloc[i] = conv_w[d * 9 + i];
    float bias = conv_b[d];
    for (int e = threadIdx.x; e < LL; e += 256) {
        int h = e / WW, w = e % WW;
        float acc = bias;
        #pragma unroll
        for (int dy = -1; dy <= 1; ++dy) {
            int hh = h + dy; if (hh < 0 || hh >= HH) continue;
            #pragma unroll
            for (int dx = -1; dx <= 1; ++dx) {
                int ww = w + dx; if (ww < 0 || ww >= WW) continue;
                acc += src[hh * WW + ww] * wloc[(dy + 1) * 3 + (dx + 1)];
            }
        }
        float sig = 1.f / (1.f + __expf(-acc));
        float v = acc * sig;
        v1[bd * LL + e] = v;
        tile[h * 57 + w] = v;
    }
    __syncthreads();
    for (int e = threadIdx.x; e < LL; e += 256) {
        int w = e / HH, h = e % HH;
        v2[bd * LL + e] = tile[h * 57 + w];
    }
}

// ---------------- K4: x_proj + dt_proj + softplus (tiled mini-GEMM) ----------------
// grid (NT, 2, BZ) x 256.  Block: 64 positions, both k's of one direction.
__global__ __launch_bounds__(256) void k4_proj(const float* __restrict__ v1,
    const float* __restrict__ v2, const float* __restrict__ xpw,
    const float* __restrict__ dtw, const float* __restrict__ dtb,
    float* __restrict__ dt_s, float* __restrict__ B_s, float* __restrict__ C_s) {
    int t0 = blockIdx.x * 64;
    int dir = blockIdx.y;
    int b = blockIdx.z;
    int lane = threadIdx.x & 63, wv = threadIdx.x >> 6;
    int kA = dir, kB = dir + 2;
    __shared__ float xs_l[DI * 64];    // [d][p], 49152 B
    __shared__ float dtr[2 * RR * 64]; // low-rank rows [ki][r][p]
    const float* src = (dir == 0 ? v1 : v2) + b * DI * LL + t0;
    for (int e = threadIdx.x; e < DI * 64; e += 256) {
        int d = e >> 6, p = e & 63;
        xs_l[e] = src[d * LL + p];     // e>>6 constant per wave-iter, p coalesced
    }
    __syncthreads();
    // 76 output rows (kA:38, kB:38); wave wv does rows wv*19 .. wv*19+18
    float acc[19];
    #pragma unroll
    for (int i = 0; i < 19; ++i) acc[i] = 0.f;
    const float* wb[19];
    int rowk[19], rowc[19];
    #pragma unroll
    for (int i = 0; i < 19; ++i) {
        int r = wv * 19 + i;
        int kloc = (r < 38) ? kA : kB;
        int c = (r < 38) ? r : r - 38;
        rowk[i] = kloc; rowc[i] = c;
        wb[i] = xpw + (kloc * 38 + c) * DI;
    }
    for (int d = 0; d < DI; ++d) {
        float xv = xs_l[d * 64 + lane];
        #pragma unroll
        for (int i = 0; i < 19; ++i)
            acc[i] += xv * wb[i][d];
    }
    int p = t0 + lane;
    #pragma unroll
    for (int i = 0; i < 19; ++i) {
        int kloc = rowk[i], c = rowc[i];
        int ki = (kloc == kA) ? 0 : 1;
        if (c < RR) {
            dtr[(ki * RR + c) * 64 + lane] = acc[i];
        } else if (c < RR + NS) {
            B_s[((b * 4 + kloc) * NS + (c - RR)) * LL + p] = acc[i];
        } else {
            C_s[((b * 4 + kloc) * NS + (c - RR - NS)) * LL + p] = acc[i];
        }
    }
    __syncthreads();
    // dt phase: 2*192 = 384 rows; wave wv does 96 rows, position = lane
    for (int i = 0; i < 96; ++i) {
        int idx = wv * 96 + i;
        int ki = idx / DI;             // 0 -> kA, 1 -> kB
        int d = idx % DI;
        int kloc = ki ? kB : kA;
        float a = dtb[kloc * DI + d];
        const float* wr = dtw + (kloc * DI + d) * RR;
        #pragma unroll
        for (int r = 0; r < RR; ++r)
            a += dtr[(ki * RR + r) * 64 + lane] * wr[r];
        dt_s[((b * 4 + kloc) * DI + d) * LL + p] = softplusf(a);
    }
}

// ---------------- K5a: scan phase 1 — per-chunk local scan ----------------
__global__ __launch_bounds__(64) void k5a_scan(float* __restrict__ dt_s,
    const float* __restrict__ B_s, const float* __restrict__ C_s,
    const float* __restrict__ v1, const float* __restrict__ v2,
    const float* __restrict__ A_logs, float* __restrict__ y_scan,
    float* __restrict__ hlast) {
    int bx = blockIdx.x;
    int dg = bx % 48, c = bx / 48;
    int k = blockIdx.y, b = blockIdx.z;
    int d0 = dg * 4;
    int lane = threadIdx.x;
    int dl = lane >> 4, n = lane & 15;
    __shared__ float dt_l[4 * 65], u_l[4 * 65], b_l[16 * 65], c_l[16 * 65];
    __shared__ float y_l[4 * 65], cd_l[4 * 65];
    int d = d0 + dl;
    int bk = b * 4 + k;
    float Av = -__expf(A_logs[(k * DI + d) * NS + n]);
    bool fwd = (k < 2);
    int s0 = fwd ? c * 64 : (LL - (c + 1) * 64);
    const float* dtp = dt_s + (bk * DI + d0) * LL;
    const float* up = ((k == 0 || k == 2) ? v1 : v2) + (b * DI + d0) * LL;
    const float* bp = B_s + (bk * NS) * LL;
    const float* cp = C_s + (bk * NS) * LL;
    float* yp = y_scan + (bk * DI + d0) * LL;
    #pragma unroll
    for (int r = 0; r < 4; ++r) {
        dt_l[r * 65 + lane] = dtp[r * LL + s0 + lane];
        u_l[r * 65 + lane]  = up[r * LL + s0 + lane];
    }
    #pragma unroll
    for (int r = 0; r < 16; ++r) {
        b_l[r * 65 + lane] = bp[r * LL + s0 + lane];
        c_l[r * 65 + lane] = cp[r * LL + s0 + lane];
    }
    __syncthreads();
    float h = 0.f, run = 0.f;
    #pragma unroll 4
    for (int jj = 0; jj < 64; ++jj) {
        int j = fwd ? jj : 63 - jj;
        float dtv = dt_l[dl * 65 + j];
        float uv  = u_l[dl * 65 + j];
        float bv  = b_l[n * 65 + j];
        float cv  = c_l[n * 65 + j];
        run += dtv;
        h = __expf(dtv * Av) * h + dtv * bv * uv;
        float y = h * cv;
        y += __shfl_xor(y, 1);
        y += __shfl_xor(y, 2);
        y += __shfl_xor(y, 4);
        y += __shfl_xor(y, 8);
        if (n == 0) { y_l[dl * 65 + j] = y; cd_l[dl * 65 + j] = run; }
    }
    __syncthreads();
    #pragma unroll
    for (int r = 0; r < 4; ++r) {
        yp[r * LL + s0 + lane] = y_l[r * 65 + lane];
        dt_s[(bk * DI + d0 + r) * LL + s0 + lane] = cd_l[r * 65 + lane];
    }
    hlast[(bk * NC + c) * (48 * 64) + dg * 64 + lane] = h;
}

// ---------------- K5c: scan phase 2 — serial chunk combine ----------------
__global__ __launch_bounds__(64) void k5c_comb(const float* __restrict__ hlast,
    const float* __restrict__ cumdt, const float* __restrict__ A_logs,
    float* __restrict__ hin) {
    int dg = blockIdx.x, k = blockIdx.y, b = blockIdx.z;
    int lane = threadIdx.x, dl = lane >> 4, n = lane & 15;
    int d = dg * 4 + dl;
    int bk = b * 4 + k;
    bool fwd = (k < 2);
    float Av = -__expf(A_logs[(k * DI + d) * NS + n]);
    float H = 0.f;
    for (int c = 0; c < NC; ++c) {
        hin[(bk * NC + c) * (48 * 64) + dg * 64 + lane] = H;
        int s0 = fwd ? c * 64 : (LL - (c + 1) * 64);
        int jlast = fwd ? s0 + 63 : s0;
        float T = cumdt[(bk * DI + d) * LL + jlast];
        float hl = hlast[(bk * NC + c) * (48 * 64) + dg * 64 + lane];
        H = hl + __expf(Av * T) * H;
    }
}

// ---------------- K5d: scan phase 3 — parallel correction ----------------
__global__ __launch_bounds__(256) void k5d_corr(const float* __restrict__ cumdt,
    const float* __restrict__ C_s, const float* __restrict__ hin,
    const float* __restrict__ A_logs, float* __restrict__ y_scan) {
    int t = blockIdx.x;
    int k = blockIdx.y, b = blockIdx.z;
    bool fwd = (k < 2);
    int tile = fwd ? (t + 1) : t;
    int c = fwd ? tile : (48 - tile);
    int s0 = tile * 64;
    int lane = threadIdx.x & 63, wv = threadIdx.x >> 6;
    int bk = b * 4 + k;
    __shared__ float c_l[16 * 65];
    for (int e = threadIdx.x; e < 16 * 64; e += 256) {
        int n = e >> 6, s = e & 63;
        c_l[n * 65 + s] = C_s[(bk * NS + n) * LL + s0 + s];
    }
    __syncthreads();
    for (int dd = 0; dd < 48; ++dd) {
        int d = wv * 48 + dd;
        float cd = cumdt[(bk * DI + d) * LL + s0 + lane];
        const float* hp = hin + (bk * NC + c) * (48 * 64) + d * 16;
        const float* ap = A_logs + (k * DI + d) * NS;
        float acc = 0.f;
        #pragma unroll
        for (int n = 0; n < 16; ++n) {
            float Av = -__expf(ap[n]);
            acc += c_l[n * 65 + lane] * __expf(Av * cd) * hp[n];
        }
        y_scan[(bk * DI + d) * LL + s0 + lane] += acc;
    }
}

// ---------------- K5b: transpose y for k=1,3 ----------------
__global__ __launch_bounds__(64) void k5b_tr(const float* __restrict__ y_scan,
                                             float* __restrict__ y13t) {
    int idx = blockIdx.x;
    int d = idx % DI;
    int bk = idx / DI;
    int kk = bk % 2, b = bk / 2;
    int k = (kk == 0) ? 1 : 3;
    __shared__ float tile[HH * 57];
    const float* src = y_scan + ((b * 4 + k) * DI + d) * LL;
    for (int e = threadIdx.x; e < LL; e += 64) {
        int w = e / HH, h = e % HH;
        tile[h * 57 + w] = src[e];
    }
    __syncthreads();
    float* dst = y13t + idx * LL;
    for (int e = threadIdx.x; e < LL; e += 64) {
        int h = e / WW, w = e % WW;
        dst[e] = tile[h * 57 + w];
    }
}

// ---------------- K6: gather 4 dirs + D*u + out_norm + silu(z) gate -> t ----------------
__global__ __launch_bounds__(256) void k6_gather(const float* __restrict__ y_scan,
    const float* __restrict__ y13t, const float* __restrict__ v1,
    const float* __restrict__ z_buf, const float* __restrict__ Ds,
    const float* __restrict__ ong, const float* __restrict__ onb,
    float* __restrict__ t_buf) {
    int t0 = blockIdx.x * 64;
    int b = blockIdx.y;
    int lane = threadIdx.x & 63, wv = threadIdx.x >> 6;
    int p = t0 + lane;
    __shared__ float yv[DI * 65];
    __shared__ float ps[4][64], ps2[4][64];
    float s = 0.f, s2 = 0.f;
    for (int d = wv * 48; d < wv * 48 + 48; ++d) {
        float dsum = Ds[d] + Ds[DI + d] + Ds[2 * DI + d] + Ds[3 * DI + d];
        float val = y_scan[((b * 4 + 0) * DI + d) * LL + p]
                  + y_scan[((b * 4 + 2) * DI + d) * LL + p]
                  + y13t[((b * 2 + 0) * DI + d) * LL + p]
                  + y13t[((b * 2 + 1) * DI + d) * LL + p]
                  + v1[(b * DI + d) * LL + p] * dsum;
        yv[d * 65 + lane] = val;
        s += val; s2 += val * val;
    }
    ps[wv][lane] = s; ps2[wv][lane] = s2;
    __syncthreads();
    float st = 0.f, st2 = 0.f;
    #pragma unroll
    for (int i = 0; i < 4; ++i) { st += ps[i][lane]; st2 += ps2[i][lane]; }
    float m = st * (1.f / 192.f);
    float inv = rsqrtf(st2 * (1.f / 192.f) - m * m + 1e-5f);
    for (int d = wv * 48; d < wv * 48 + 48; ++d) {
        float val = (yv[d * 65 + lane] - m) * inv * ong[d] + onb[d];
        float zz = z_buf[(b * DI + d) * LL + p];
        float sig = 1.f / (1.f + __expf(-zz));
        t_buf[(b * DI + d) * LL + p] = val * zz * sig;
    }
}

// ---------------- K7: fused matmul (conv_out | t@W2) + fus_b + LN + residual -----------
__global__ __launch_bounds__(256) void k7_final(const float* __restrict__ t_buf,
    const float* __restrict__ conv_out, const float* __restrict__ W2,
    const float* __restrict__ fus_w, const float* __restrict__ fus_b,
    const float* __restrict__ flg, const float* __restrict__ flb,
    const float* __restrict__ x, float* __restrict__ out) {
    int t0 = blockIdx.x * 64;
    int b = blockIdx.y;
    int lane = threadIdx.x & 63, wv = threadIdx.x >> 6;
    int p = t0 + lane;
    __shared__ float ct[64 * 97];
    __shared__ float res[64 * 97];
    __shared__ float ps[4][64], ps2[4][64];
    const float* cb = conv_out + (b * LL + t0) * CC;
    for (int e = threadIdx.x; e < 64 * CC; e += 256) {
        int pl = e / CC, c = e % CC;
        ct[pl * 97 + c] = cb[e];
    }
    __syncthreads();
    float acc[24];
    #pragma unroll
    for (int o = 0; o < 24; ++o) acc[o] = fus_b[wv * 24 + o];
    for (int d = 0; d < DI; ++d) {
        float tv = t_buf[(b * DI + d) * LL + p];
        const float* w2 = W2 + (wv * 24) * DI + d;
        #pragma unroll
        for (int o = 0; o < 24; ++o) acc[o] += tv * w2[o * DI];
    }
    for (int c = 0; c < CC; ++c) {
        float cv = ct[lane * 97 + c];
        const float* fw = fus_w + (wv * 24) * DI + c;
        #pragma unroll
        for (int o = 0; o < 24; ++o) acc[o] += cv * fw[o * DI];
    }
    float s = 0.f, s2 = 0.f;
    #pragma unroll
    for (int o = 0; o < 24; ++o) { s += acc[o]; s2 += acc[o] * acc[o]; }
    ps[wv][lane] = s; ps2[wv][lane] = s2;
    __syncthreads();
    float st = 0.f, st2 = 0.f;
    #pragma unroll
    for (int i = 0; i < 4; ++i) { st += ps[i][lane]; st2 += ps2[i][lane]; }
    float m = st * (1.f / 96.f);
    float inv = rsqrtf(st2 * (1.f / 96.f) - m * m + 1e-5f);
    #pragma unroll
    for (int o = 0; o < 24; ++o) {
        int oo = wv * 24 + o;
        res[lane * 97 + oo] = (acc[o] - m) * inv * flg[oo] + flb[oo];
    }
    __syncthreads();
    const float* xb = x + (b * LL + t0) * CC;
    float* ob = out + (b * LL + t0) * CC;
    for (int e = threadIdx.x; e < 64 * CC; e += 256) {
        int pl = e / CC, o = e % CC;
        ob[e] = xb[e] + res[pl * 97 + o];
    }
}

extern "C" void kernel_launch(void* const* d_in, const int* in_sizes, int n_in,
                              void* d_out, int out_size, void* d_ws, size_t ws_size,
                              hipStream_t stream) {
    const float* x        = (const float*)d_in[0];
    const float* dw_w     = (const float*)d_in[1];
    const float* dw_b     = (const float*)d_in[2];
    const float* bn1_g    = (const float*)d_in[3];
    const float* bn1_b    = (const float*)d_in[4];
    const float* bn1_m    = (const float*)d_in[5];
    const float* bn1_v    = (const float*)d_in[6];
    const float* pw_w     = (const float*)d_in[7];
    const float* pw_b     = (const float*)d_in[8];
    const float* bn2_g    = (const float*)d_in[9];
    const float* bn2_b    = (const float*)d_in[10];
    const float* bn2_m    = (const float*)d_in[11];
    const float* bn2_v    = (const float*)d_in[12];
    const float* ln_g     = (const float*)d_in[13];
    const float* ln_b     = (const float*)d_in[14];
    const float* ipw      = (const float*)d_in[15];
    const float* conv_w   = (const float*)d_in[16];
    const float* conv_b   = (const float*)d_in[17];
    const float* xpw      = (const float*)d_in[18];
    const float* dtw      = (const float*)d_in[19];
    const float* dtb      = (const float*)d_in[20];
    const float* A_logs   = (const float*)d_in[21];
    const float* Ds       = (const float*)d_in[22];
    const float* ong      = (const float*)d_in[23];
    const float* onb      = (const float*)d_in[24];
    const float* opw      = (const float*)d_in[25];
    const float* fus_w    = (const float*)d_in[26];
    const float* fus_b    = (const float*)d_in[27];
    const float* flg      = (const float*)d_in[28];
    const float* flb      = (const float*)d_in[29];

    float* ws = (float*)d_ws;
    float* conv_out = ws + OFF_CONV;
    float* xm_raw   = ws + OFF_XMRAW;
    float* z_buf    = ws + OFF_Z;
    float* v1       = ws + OFF_V1;
    float* v2       = ws + OFF_V2;
    float* dt_s     = ws + OFF_DT;     // becomes cumdt after k5a (in place)
    float* B_s      = ws + OFF_BS;
    float* C_s      = ws + OFF_CS;
    float* y_scan   = ws + OFF_Y;
    float* y13t     = ws + OFF_Y13;
    float* t_buf    = ws + OFF_T;
    float* W2       = ws + OFF_W2;
    float* hlast    = xm_raw;          // alias: xm_raw dead after k3
    float* hin      = t_buf;           // alias: t_buf dead until k6
    float* out      = (float*)d_out;

    k0_w2<<<dim3((CC * DI + 63) / 64), dim3(64), 0, stream>>>(fus_w, opw, W2);
    k1_conv<<<dim3(BZ * HH), dim3(256), 0, stream>>>(x, dw_w, dw_b, bn1_g, bn1_b, bn1_m, bn1_v,
                                                     pw_w, pw_b, bn2_g, bn2_b, bn2_m, bn2_v, conv_out);
    k2_inproj<<<dim3(NT, 4, BZ), dim3(256), 0, stream>>>(x, ln_g, ln_b, ipw, xm_raw, z_buf);
    k3_dw<<<dim3(BZ * DI), dim3(256), 0, stream>>>(xm_raw, conv_w, conv_b, v1, v2);
    k4_proj<<<dim3(NT, 2, BZ), dim3(256), 0, stream>>>(v1, v2, xpw, dtw, dtb, dt_s, B_s, C_s);
    k5a_scan<<<dim3(48 * NC, 4, BZ), dim3(64), 0, stream>>>(dt_s, B_s, C_s, v1, v2, A_logs, y_scan, hlast);
    k5c_comb<<<dim3(48, 4, BZ), dim3(64), 0, stream>>>(hlast, dt_s, A_logs, hin);
    k5d_corr<<<dim3(48, 4, BZ), dim3(256), 0, stream>>>(dt_s, C_s, hin, A_logs, y_scan);
    k5b_tr<<<dim3(BZ * 2 * DI), dim3(64), 0, stream>>>(y_scan, y13t);
    k6_gather<<<dim3(NT, BZ), dim3(256), 0, stream>>>(y_scan, y13t, v1, z_buf, Ds, ong, onb, t_buf);
    k7_final<<<dim3(NT, BZ), dim3(256), 0, stream>>>(t_buf, conv_out, W2, fus_w, fus_b, flg, flb, x, out);
}

// Round 4
// 608.118 us; speedup vs baseline: 2.1496x; 1.0453x over previous
//
#include <hip/hip_runtime.h>
#include <math.h>

// Problem constants
#define BZ 2
#define HH 56
#define WW 56
#define LL 3136      // 56*56
#define CC 96        // DIM
#define DI 192       // DINNER
#define NS 16        // DSTATE
#define RR 6         // DTRANK
#define NT 49        // LL/64
#define NC 49        // chunks for scan

// Workspace layout (floats)
#define OFF_CONV   0
#define OFF_XMRAW  602112
#define OFF_Z      1806336
#define OFF_V1     3010560
#define OFF_V2     4214784
#define OFF_DT     5419008
#define OFF_BS     10235904
#define OFF_CS     10637312
#define OFF_Y      11038720
#define OFF_Y13    15855616
#define OFF_T      18264064
#define OFF_W2     19468288
// total 19486720 floats = ~78 MB

__device__ __forceinline__ float softplusf(float x) {
    if (x > 20.f) return x;
    return log1pf(__expf(x));
}

// ---------------- K0: W2[o][d] = sum_j fus_w[o][96+j] * out_proj_w[j][d] ----------------
__global__ __launch_bounds__(64) void k0_w2(const float* __restrict__ fus_w,
                                            const float* __restrict__ opw,
                                            float* __restrict__ W2) {
    int i = blockIdx.x * 64 + threadIdx.x;
    if (i >= CC * DI) return;
    int o = i / DI, d = i % DI;
    float acc = 0.f;
    for (int j = 0; j < CC; ++j)
        acc += fus_w[o * DI + CC + j] * opw[j * DI + d];
    W2[i] = acc;
}

// ---------------- K1: conv path -> conv_out (B,L,96) NHWC ----------------
// Phase A: dwconv+bn1+relu into LDS row tile. Phase B: mini-GEMM, 24 acc/thread,
// wave-uniform weight rows (s_load), 1 LDS read per 24 FMA.
__global__ __launch_bounds__(256) void k1_conv(const float* __restrict__ x,
    const float* __restrict__ dw_w, const float* __restrict__ dw_b,
    const float* __restrict__ bn1_g, const float* __restrict__ bn1_b,
    const float* __restrict__ bn1_m, const float* __restrict__ bn1_v,
    const float* __restrict__ pw_w, const float* __restrict__ pw_b,
    const float* __restrict__ bn2_g, const float* __restrict__ bn2_b,
    const float* __restrict__ bn2_m, const float* __restrict__ bn2_v,
    float* __restrict__ conv_out) {
    int bh = blockIdx.x;
    int b = bh / HH, h = bh % HH;
    __shared__ float row[WW * 97];        // [w][c] padded
    int t = threadIdx.x;
    for (int e = t; e < WW * CC; e += 256) {
        int w = e / CC, c = e % CC;
        float acc = dw_b[c];
        #pragma unroll
        for (int dy = -1; dy <= 1; ++dy) {
            int hh = h + dy; if (hh < 0 || hh >= HH) continue;
            #pragma unroll
            for (int dx = -1; dx <= 1; ++dx) {
                int ww = w + dx; if (ww < 0 || ww >= WW) continue;
                acc += x[((b * HH + hh) * WW + ww) * CC + c] * dw_w[c * 9 + (dy + 1) * 3 + (dx + 1)];
            }
        }
        float inv = rsqrtf(bn1_v[c] + 1e-5f);
        float v = (acc - bn1_m[c]) * inv * bn1_g[c] + bn1_b[c];
        row[w * 97 + c] = fmaxf(v, 0.f);
    }
    __syncthreads();
    int lane = t & 63, wv = t >> 6;     // lane = w (<56), wv = output slice of 24
    if (lane < WW) {
        float acc[24];
        #pragma unroll
        for (int j = 0; j < 24; ++j) acc[j] = pw_b[wv * 24 + j];
        const float* wb = pw_w + (wv * 24) * CC;
        for (int c = 0; c < CC; ++c) {
            float xv = row[lane * 97 + c];
            #pragma unroll
            for (int j = 0; j < 24; ++j)
                acc[j] += xv * wb[j * CC + c];     // wave-uniform -> s_load
        }
        int o0 = wv * 24;
        float* ob = conv_out + ((b * HH + h) * WW + lane) * CC + o0;
        #pragma unroll
        for (int j = 0; j < 24; ++j) {
            int o = o0 + j;
            float inv = rsqrtf(bn2_v[o] + 1e-5f);
            ob[j] = (acc[j] - bn2_m[o]) * inv * bn2_g[o] + bn2_b[o];
        }
    }
}

// ---------------- K2: LN + in_proj (tiled) -> xm_raw (B,192,L), z (B,192,L) -------------
__global__ __launch_bounds__(256) void k2_inproj(const float* __restrict__ x,
    const float* __restrict__ ln_g, const float* __restrict__ ln_b,
    const float* __restrict__ ipw,
    float* __restrict__ xm_raw, float* __restrict__ z_buf) {
    int t0 = blockIdx.x * 64;
    int og = blockIdx.y;
    int b = blockIdx.z;
    int lane = threadIdx.x & 63, wv = threadIdx.x >> 6;
    __shared__ float xt[64 * 97];      // [p][c]
    __shared__ float xn[96 * 65];      // [c][p] normalized
    __shared__ float ps[4][64], ps2[4][64];
    const float* xb = x + (b * LL + t0) * CC;
    for (int e = threadIdx.x; e < 64 * CC; e += 256) {
        int p = e / CC, c = e % CC;
        xt[p * 97 + c] = xb[e];
    }
    __syncthreads();
    float s = 0.f, s2 = 0.f;
    #pragma unroll
    for (int j = 0; j < 24; ++j) {
        float v = xt[lane * 97 + wv * 24 + j];
        s += v; s2 += v * v;
    }
    ps[wv][lane] = s; ps2[wv][lane] = s2;
    __syncthreads();
    float st = 0.f, st2 = 0.f;
    #pragma unroll
    for (int i = 0; i < 4; ++i) { st += ps[i][lane]; st2 += ps2[i][lane]; }
    float m = st * (1.f / 96.f);
    float inv = rsqrtf(st2 * (1.f / 96.f) - m * m + 1e-5f);
    #pragma unroll
    for (int j = 0; j < 24; ++j) {
        int c = wv * 24 + j;
        xn[c * 65 + lane] = (xt[lane * 97 + c] - m) * inv * ln_g[c] + ln_b[c];
    }
    __syncthreads();
    float acc[24];
    #pragma unroll
    for (int j = 0; j < 24; ++j) acc[j] = 0.f;
    const float* wbase = ipw + (og * 96 + wv * 24) * CC;
    for (int c = 0; c < CC; ++c) {
        float xv = xn[c * 65 + lane];
        #pragma unroll
        for (int j = 0; j < 24; ++j)
            acc[j] += xv * wbase[j * CC + c];
    }
    int p = t0 + lane;
    #pragma unroll
    for (int j = 0; j < 24; ++j) {
        int out = og * 96 + wv * 24 + j;
        if (out < DI) xm_raw[(b * DI + out) * LL + p] = acc[j];
        else          z_buf[(b * DI + (out - DI)) * LL + p] = acc[j];
    }
}

// ---------------- K3: dwconv3 + SiLU -> v1 (row-major), v2 (col-major) ----------------
__global__ __launch_bounds__(256) void k3_dw(const float* __restrict__ xm_raw,
    const float* __restrict__ conv_w, const float* __restrict__ conv_b,
    float* __restrict__ v1, float* __restrict__ v2) {
    int bd = blockIdx.x;
    int d = bd % DI;
    __shared__ float tile[HH * 57];
    const float* src = xm_raw + bd * LL;
    float wloc[9];
    #pragma unroll
    for (int i = 0; i < 9; ++i) wloc[i] = conv_w[d * 9 + i];
    float bias = conv_b[d];
    for (int e = threadIdx.x; e < LL; e += 256) {
        int h = e / WW, w = e % WW;
        float acc = bias;
        #pragma unroll
        for (int dy = -1; dy <= 1; ++dy) {
            int hh = h + dy; if (hh < 0 || hh >= HH) continue;
            #pragma unroll
            for (int dx = -1; dx <= 1; ++dx) {
                int ww = w + dx; if (ww < 0 || ww >= WW) continue;
                acc += src[hh * WW + ww] * wloc[(dy + 1) * 3 + (dx + 1)];
            }
        }
        float sig = 1.f / (1.f + __expf(-acc));
        float v = acc * sig;
        v1[bd * LL + e] = v;
        tile[h * 57 + w] = v;
    }
    __syncthreads();
    for (int e = threadIdx.x; e < LL; e += 256) {
        int w = e / HH, h = e % HH;
        v2[bd * LL + e] = tile[h * 57 + w];
    }
}

// ---------------- K4: x_proj + dt_proj + softplus (tiled mini-GEMM) ----------------
__global__ __launch_bounds__(256) void k4_proj(const float* __restrict__ v1,
    const float* __restrict__ v2, const float* __restrict__ xpw,
    const float* __restrict__ dtw, const float* __restrict__ dtb,
    float* __restrict__ dt_s, float* __restrict__ B_s, float* __restrict__ C_s) {
    int t0 = blockIdx.x * 64;
    int dir = blockIdx.y;
    int b = blockIdx.z;
    int lane = threadIdx.x & 63, wv = threadIdx.x >> 6;
    int kA = dir, kB = dir + 2;
    __shared__ float xs_l[DI * 64];
    __shared__ float dtr[2 * RR * 64];
    const float* src = (dir == 0 ? v1 : v2) + b * DI * LL + t0;
    for (int e = threadIdx.x; e < DI * 64; e += 256) {
        int d = e >> 6, p = e & 63;
        xs_l[e] = src[d * LL + p];
    }
    __syncthreads();
    float acc[19];
    #pragma unroll
    for (int i = 0; i < 19; ++i) acc[i] = 0.f;
    const float* wb[19];
    int rowk[19], rowc[19];
    #pragma unroll
    for (int i = 0; i < 19; ++i) {
        int r = wv * 19 + i;
        int kloc = (r < 38) ? kA : kB;
        int c = (r < 38) ? r : r - 38;
        rowk[i] = kloc; rowc[i] = c;
        wb[i] = xpw + (kloc * 38 + c) * DI;
    }
    for (int d = 0; d < DI; ++d) {
        float xv = xs_l[d * 64 + lane];
        #pragma unroll
        for (int i = 0; i < 19; ++i)
            acc[i] += xv * wb[i][d];
    }
    int p = t0 + lane;
    #pragma unroll
    for (int i = 0; i < 19; ++i) {
        int kloc = rowk[i], c = rowc[i];
        int ki = (kloc == kA) ? 0 : 1;
        if (c < RR) {
            dtr[(ki * RR + c) * 64 + lane] = acc[i];
        } else if (c < RR + NS) {
            B_s[((b * 4 + kloc) * NS + (c - RR)) * LL + p] = acc[i];
        } else {
            C_s[((b * 4 + kloc) * NS + (c - RR - NS)) * LL + p] = acc[i];
        }
    }
    __syncthreads();
    for (int i = 0; i < 96; ++i) {
        int idx = wv * 96 + i;
        int ki = idx / DI;
        int d = idx % DI;
        int kloc = ki ? kB : kA;
        float a = dtb[kloc * DI + d];
        const float* wr = dtw + (kloc * DI + d) * RR;
        #pragma unroll
        for (int r = 0; r < RR; ++r)
            a += dtr[(ki * RR + r) * 64 + lane] * wr[r];
        dt_s[((b * 4 + kloc) * DI + d) * LL + p] = softplusf(a);
    }
}

// ---------------- K5a: scan phase 1 — per-chunk local scan, lane = d ----------------
// grid (3*NC, 4, BZ) x 64: one wave per (b, k, chunk, 64-d group).
// Lane holds all 16 n-states in registers; B/C are wave-uniform scalar loads.
// Writes: y (local) into y_scan; inclusive cumdt in-place into dt_s; hlast.
__global__ __launch_bounds__(64) void k5a_scan(float* __restrict__ dt_s,
    const float* __restrict__ B_s, const float* __restrict__ C_s,
    const float* __restrict__ v1, const float* __restrict__ v2,
    const float* __restrict__ A_logs, float* __restrict__ y_scan,
    float* __restrict__ hlast) {
    int bx = blockIdx.x;
    int dg = bx % 3, c = bx / 3;
    int k = blockIdx.y, b = blockIdx.z;
    int bk = b * 4 + k;
    int lane = threadIdx.x;
    int d0 = dg * 64, d = d0 + lane;
    bool fwd = (k < 2);
    int s0 = fwd ? c * 64 : (LL - (c + 1) * 64);
    __shared__ float dt_l[64 * 65];    // [r][j]; overwritten with cumdt
    __shared__ float u_l[64 * 65];     // [r][j]; overwritten with y
    // A row (16 contiguous floats per lane), pre-scaled for exp2
    float Ae[16];
    const float* ap = A_logs + (k * DI + d) * NS;
    #pragma unroll
    for (int n = 0; n < 16; ++n) Ae[n] = -__expf(ap[n]) * 1.442695040888963f;
    // stage dt,u tiles (coalesced rows)
    const float* dtp = dt_s + (bk * DI + d0) * LL + s0;
    const float* up  = ((k == 0 || k == 2) ? v1 : v2) + (b * DI + d0) * LL + s0;
    #pragma unroll 8
    for (int r = 0; r < 64; ++r) {
        dt_l[r * 65 + lane] = dtp[r * LL + lane];
        u_l[r * 65 + lane]  = up[r * LL + lane];
    }
    __syncthreads();
    float h[16];
    #pragma unroll
    for (int n = 0; n < 16; ++n) h[n] = 0.f;
    float cum = 0.f;
    const float* Bb = B_s + (bk * NS) * LL + s0;
    const float* Cb = C_s + (bk * NS) * LL + s0;
    for (int jj = 0; jj < 64; ++jj) {
        int j = fwd ? jj : 63 - jj;
        float dtv = dt_l[lane * 65 + j];
        float uv  = u_l[lane * 65 + j];
        float du = dtv * uv;
        cum += dtv;
        float y = 0.f;
        #pragma unroll
        for (int n = 0; n < 16; ++n) {
            float bv = Bb[n * LL + j];        // wave-uniform -> s_load
            float cv = Cb[n * LL + j];        // wave-uniform -> s_load
            h[n] = exp2f(dtv * Ae[n]) * h[n] + du * bv;
            y += h[n] * cv;
        }
        u_l[lane * 65 + j] = y;               // overwrite own slot
        dt_l[lane * 65 + j] = cum;            // overwrite own slot
    }
    __syncthreads();
    // flush y and cumdt (coalesced rows)
    float* yp = y_scan + (bk * DI + d0) * LL + s0;
    float* cp = dt_s + (bk * DI + d0) * LL + s0;
    #pragma unroll 8
    for (int r = 0; r < 64; ++r) {
        yp[r * LL + lane] = u_l[r * 65 + lane];
        cp[r * LL + lane] = dt_l[r * 65 + lane];
    }
    // hlast: 16 contiguous floats per lane (same linear layout as before: d*16+n)
    float4* hp4 = (float4*)(hlast + (bk * NC + c) * (DI * NS) + d * NS);
    hp4[0] = make_float4(h[0], h[1], h[2], h[3]);
    hp4[1] = make_float4(h[4], h[5], h[6], h[7]);
    hp4[2] = make_float4(h[8], h[9], h[10], h[11]);
    hp4[3] = make_float4(h[12], h[13], h[14], h[15]);
}

// ---------------- K5c: scan phase 2 — serial chunk combine ----------------
__global__ __launch_bounds__(64) void k5c_comb(const float* __restrict__ hlast,
    const float* __restrict__ cumdt, const float* __restrict__ A_logs,
    float* __restrict__ hin) {
    int dg = blockIdx.x, k = blockIdx.y, b = blockIdx.z;
    int lane = threadIdx.x, dl = lane >> 4, n = lane & 15;
    int d = dg * 4 + dl;
    int bk = b * 4 + k;
    bool fwd = (k < 2);
    float Av = -__expf(A_logs[(k * DI + d) * NS + n]);
    float H = 0.f;
    for (int c = 0; c < NC; ++c) {
        hin[(bk * NC + c) * (48 * 64) + dg * 64 + lane] = H;
        int s0 = fwd ? c * 64 : (LL - (c + 1) * 64);
        int jlast = fwd ? s0 + 63 : s0;
        float T = cumdt[(bk * DI + d) * LL + jlast];
        float hl = hlast[(bk * NC + c) * (48 * 64) + dg * 64 + lane];
        H = hl + __expf(Av * T) * H;
    }
}

// ---------------- K5d: scan phase 3 — parallel correction ----------------
__global__ __launch_bounds__(256) void k5d_corr(const float* __restrict__ cumdt,
    const float* __restrict__ C_s, const float* __restrict__ hin,
    const float* __restrict__ A_logs, float* __restrict__ y_scan) {
    int t = blockIdx.x;
    int k = blockIdx.y, b = blockIdx.z;
    bool fwd = (k < 2);
    int tile = fwd ? (t + 1) : t;
    int c = fwd ? tile : (48 - tile);
    int s0 = tile * 64;
    int lane = threadIdx.x & 63, wv = threadIdx.x >> 6;
    int bk = b * 4 + k;
    __shared__ float c_l[16 * 65];
    for (int e = threadIdx.x; e < 16 * 64; e += 256) {
        int n = e >> 6, s = e & 63;
        c_l[n * 65 + s] = C_s[(bk * NS + n) * LL + s0 + s];
    }
    __syncthreads();
    for (int dd = 0; dd < 48; ++dd) {
        int d = wv * 48 + dd;
        float cd = cumdt[(bk * DI + d) * LL + s0 + lane];
        const float* hp = hin + (bk * NC + c) * (48 * 64) + d * 16;
        const float* ap = A_logs + (k * DI + d) * NS;
        float acc = 0.f;
        #pragma unroll
        for (int n = 0; n < 16; ++n) {
            float Av = -__expf(ap[n]);
            acc += c_l[n * 65 + lane] * __expf(Av * cd) * hp[n];
        }
        y_scan[(bk * DI + d) * LL + s0 + lane] += acc;
    }
}

// ---------------- K5b: transpose y for k=1,3 ----------------
__global__ __launch_bounds__(64) void k5b_tr(const float* __restrict__ y_scan,
                                             float* __restrict__ y13t) {
    int idx = blockIdx.x;
    int d = idx % DI;
    int bk = idx / DI;
    int kk = bk % 2, b = bk / 2;
    int k = (kk == 0) ? 1 : 3;
    __shared__ float tile[HH * 57];
    const float* src = y_scan + ((b * 4 + k) * DI + d) * LL;
    for (int e = threadIdx.x; e < LL; e += 64) {
        int w = e / HH, h = e % HH;
        tile[h * 57 + w] = src[e];
    }
    __syncthreads();
    float* dst = y13t + idx * LL;
    for (int e = threadIdx.x; e < LL; e += 64) {
        int h = e / WW, w = e % WW;
        dst[e] = tile[h * 57 + w];
    }
}

// ---------------- K6: gather 4 dirs + D*u + out_norm + silu(z) gate -> t ----------------
__global__ __launch_bounds__(256) void k6_gather(const float* __restrict__ y_scan,
    const float* __restrict__ y13t, const float* __restrict__ v1,
    const float* __restrict__ z_buf, const float* __restrict__ Ds,
    const float* __restrict__ ong, const float* __restrict__ onb,
    float* __restrict__ t_buf) {
    int t0 = blockIdx.x * 64;
    int b = blockIdx.y;
    int lane = threadIdx.x & 63, wv = threadIdx.x >> 6;
    int p = t0 + lane;
    __shared__ float yv[DI * 65];
    __shared__ float ps[4][64], ps2[4][64];
    float s = 0.f, s2 = 0.f;
    for (int d = wv * 48; d < wv * 48 + 48; ++d) {
        float dsum = Ds[d] + Ds[DI + d] + Ds[2 * DI + d] + Ds[3 * DI + d];
        float val = y_scan[((b * 4 + 0) * DI + d) * LL + p]
                  + y_scan[((b * 4 + 2) * DI + d) * LL + p]
                  + y13t[((b * 2 + 0) * DI + d) * LL + p]
                  + y13t[((b * 2 + 1) * DI + d) * LL + p]
                  + v1[(b * DI + d) * LL + p] * dsum;
        yv[d * 65 + lane] = val;
        s += val; s2 += val * val;
    }
    ps[wv][lane] = s; ps2[wv][lane] = s2;
    __syncthreads();
    float st = 0.f, st2 = 0.f;
    #pragma unroll
    for (int i = 0; i < 4; ++i) { st += ps[i][lane]; st2 += ps2[i][lane]; }
    float m = st * (1.f / 192.f);
    float inv = rsqrtf(st2 * (1.f / 192.f) - m * m + 1e-5f);
    for (int d = wv * 48; d < wv * 48 + 48; ++d) {
        float val = (yv[d * 65 + lane] - m) * inv * ong[d] + onb[d];
        float zz = z_buf[(b * DI + d) * LL + p];
        float sig = 1.f / (1.f + __expf(-zz));
        t_buf[(b * DI + d) * LL + p] = val * zz * sig;
    }
}

// ---------------- K7: fused matmul (conv_out | t@W2) + fus_b + LN + residual -----------
__global__ __launch_bounds__(256) void k7_final(const float* __restrict__ t_buf,
    const float* __restrict__ conv_out, const float* __restrict__ W2,
    const float* __restrict__ fus_w, const float* __restrict__ fus_b,
    const float* __restrict__ flg, const float* __restrict__ flb,
    const float* __restrict__ x, float* __restrict__ out) {
    int t0 = blockIdx.x * 64;
    int b = blockIdx.y;
    int lane = threadIdx.x & 63, wv = threadIdx.x >> 6;
    int p = t0 + lane;
    __shared__ float ct[64 * 97];
    __shared__ float res[64 * 97];
    __shared__ float ps[4][64], ps2[4][64];
    const float* cb = conv_out + (b * LL + t0) * CC;
    for (int e = threadIdx.x; e < 64 * CC; e += 256) {
        int pl = e / CC, c = e % CC;
        ct[pl * 97 + c] = cb[e];
    }
    __syncthreads();
    float acc[24];
    #pragma unroll
    for (int o = 0; o < 24; ++o) acc[o] = fus_b[wv * 24 + o];
    for (int d = 0; d < DI; ++d) {
        float tv = t_buf[(b * DI + d) * LL + p];
        const float* w2 = W2 + (wv * 24) * DI + d;
        #pragma unroll
        for (int o = 0; o < 24; ++o) acc[o] += tv * w2[o * DI];
    }
    for (int c = 0; c < CC; ++c) {
        float cv = ct[lane * 97 + c];
        const float* fw = fus_w + (wv * 24) * DI + c;
        #pragma unroll
        for (int o = 0; o < 24; ++o) acc[o] += cv * fw[o * DI];
    }
    float s = 0.f, s2 = 0.f;
    #pragma unroll
    for (int o = 0; o < 24; ++o) { s += acc[o]; s2 += acc[o] * acc[o]; }
    ps[wv][lane] = s; ps2[wv][lane] = s2;
    __syncthreads();
    float st = 0.f, st2 = 0.f;
    #pragma unroll
    for (int i = 0; i < 4; ++i) { st += ps[i][lane]; st2 += ps2[i][lane]; }
    float m = st * (1.f / 96.f);
    float inv = rsqrtf(st2 * (1.f / 96.f) - m * m + 1e-5f);
    #pragma unroll
    for (int o = 0; o < 24; ++o) {
        int oo = wv * 24 + o;
        res[lane * 97 + oo] = (acc[o] - m) * inv * flg[oo] + flb[oo];
    }
    __syncthreads();
    const float* xb = x + (b * LL + t0) * CC;
    float* ob = out + (b * LL + t0) * CC;
    for (int e = threadIdx.x; e < 64 * CC; e += 256) {
        int pl = e / CC, o = e % CC;
        ob[e] = xb[e] + res[pl * 97 + o];
    }
}

extern "C" void kernel_launch(void* const* d_in, const int* in_sizes, int n_in,
                              void* d_out, int out_size, void* d_ws, size_t ws_size,
                              hipStream_t stream) {
    const float* x        = (const float*)d_in[0];
    const float* dw_w     = (const float*)d_in[1];
    const float* dw_b     = (const float*)d_in[2];
    const float* bn1_g    = (const float*)d_in[3];
    const float* bn1_b    = (const float*)d_in[4];
    const float* bn1_m    = (const float*)d_in[5];
    const float* bn1_v    = (const float*)d_in[6];
    const float* pw_w     = (const float*)d_in[7];
    const float* pw_b     = (const float*)d_in[8];
    const float* bn2_g    = (const float*)d_in[9];
    const float* bn2_b    = (const float*)d_in[10];
    const float* bn2_m    = (const float*)d_in[11];
    const float* bn2_v    = (const float*)d_in[12];
    const float* ln_g     = (const float*)d_in[13];
    const float* ln_b     = (const float*)d_in[14];
    const float* ipw      = (const float*)d_in[15];
    const float* conv_w   = (const float*)d_in[16];
    const float* conv_b   = (const float*)d_in[17];
    const float* xpw      = (const float*)d_in[18];
    const float* dtw      = (const float*)d_in[19];
    const float* dtb      = (const float*)d_in[20];
    const float* A_logs   = (const float*)d_in[21];
    const float* Ds       = (const float*)d_in[22];
    const float* ong      = (const float*)d_in[23];
    const float* onb      = (const float*)d_in[24];
    const float* opw      = (const float*)d_in[25];
    const float* fus_w    = (const float*)d_in[26];
    const float* fus_b    = (const float*)d_in[27];
    const float* flg      = (const float*)d_in[28];
    const float* flb      = (const float*)d_in[29];

    float* ws = (float*)d_ws;
    float* conv_out = ws + OFF_CONV;
    float* xm_raw   = ws + OFF_XMRAW;
    float* z_buf    = ws + OFF_Z;
    float* v1       = ws + OFF_V1;
    float* v2       = ws + OFF_V2;
    float* dt_s     = ws + OFF_DT;     // becomes cumdt after k5a (in place)
    float* B_s      = ws + OFF_BS;
    float* C_s      = ws + OFF_CS;
    float* y_scan   = ws + OFF_Y;
    float* y13t     = ws + OFF_Y13;
    float* t_buf    = ws + OFF_T;
    float* W2       = ws + OFF_W2;
    float* hlast    = xm_raw;          // alias: xm_raw dead after k3
    float* hin      = t_buf;           // alias: t_buf dead until k6
    float* out      = (float*)d_out;

    k0_w2<<<dim3((CC * DI + 63) / 64), dim3(64), 0, stream>>>(fus_w, opw, W2);
    k1_conv<<<dim3(BZ * HH), dim3(256), 0, stream>>>(x, dw_w, dw_b, bn1_g, bn1_b, bn1_m, bn1_v,
                                                     pw_w, pw_b, bn2_g, bn2_b, bn2_m, bn2_v, conv_out);
    k2_inproj<<<dim3(NT, 4, BZ), dim3(256), 0, stream>>>(x, ln_g, ln_b, ipw, xm_raw, z_buf);
    k3_dw<<<dim3(BZ * DI), dim3(256), 0, stream>>>(xm_raw, conv_w, conv_b, v1, v2);
    k4_proj<<<dim3(NT, 2, BZ), dim3(256), 0, stream>>>(v1, v2, xpw, dtw, dtb, dt_s, B_s, C_s);
    k5a_scan<<<dim3(3 * NC, 4, BZ), dim3(64), 0, stream>>>(dt_s, B_s, C_s, v1, v2, A_logs, y_scan, hlast);
    k5c_comb<<<dim3(48, 4, BZ), dim3(64), 0, stream>>>(hlast, dt_s, A_logs, hin);
    k5d_corr<<<dim3(48, 4, BZ), dim3(256), 0, stream>>>(dt_s, C_s, hin, A_logs, y_scan);
    k5b_tr<<<dim3(BZ * 2 * DI), dim3(64), 0, stream>>>(y_scan, y13t);
    k6_gather<<<dim3(NT, BZ), dim3(256), 0, stream>>>(y_scan, y13t, v1, z_buf, Ds, ong, onb, t_buf);
    k7_final<<<dim3(NT, BZ), dim3(256), 0, stream>>>(t_buf, conv_out, W2, fus_w, fus_b, flg, flb, x, out);
}

// Round 5
// 440.965 us; speedup vs baseline: 2.9644x; 1.3791x over previous
//
#include <hip/hip_runtime.h>
#include <math.h>

// Problem constants
#define BZ 2
#define HH 56
#define WW 56
#define LL 3136      // 56*56
#define CC 96        // DIM
#define DI 192       // DINNER
#define NS 16        // DSTATE
#define RR 6         // DTRANK
#define NT 49        // LL/64
#define NC 49        // chunks for scan

// Workspace layout (floats)
#define OFF_CONV   0
#define OFF_XMRAW  602112
#define OFF_Z      1806336
#define OFF_V1     3010560
#define OFF_V2     4214784
#define OFF_DT     5419008
#define OFF_BS     10235904
#define OFF_CS     10637312
#define OFF_Y      11038720
#define OFF_Y13    15855616
#define OFF_T      18264064
#define OFF_W2     19468288
// total 19486720 floats = ~78 MB

__device__ __forceinline__ float softplusf(float x) {
    if (x > 20.f) return x;
    return log1pf(__expf(x));
}

// ---------------- K0: W2[o][d] = sum_j fus_w[o][96+j] * out_proj_w[j][d] ----------------
__global__ __launch_bounds__(64) void k0_w2(const float* __restrict__ fus_w,
                                            const float* __restrict__ opw,
                                            float* __restrict__ W2) {
    int i = blockIdx.x * 64 + threadIdx.x;
    if (i >= CC * DI) return;
    int o = i / DI, d = i % DI;
    float acc = 0.f;
    for (int j = 0; j < CC; ++j)
        acc += fus_w[o * DI + CC + j] * opw[j * DI + d];
    W2[i] = acc;
}

// ---------------- K0c: negA[k][d][n] = -exp(A_logs) ----------------
__global__ __launch_bounds__(256) void k0c_negA(const float* __restrict__ A_logs,
                                                float* __restrict__ negA) {
    int i = blockIdx.x * 256 + threadIdx.x;
    if (i < 4 * DI * NS) negA[i] = -__expf(A_logs[i]);
}

// ---------------- K1: conv path -> conv_out (B,L,96) NHWC ----------------
__global__ __launch_bounds__(256) void k1_conv(const float* __restrict__ x,
    const float* __restrict__ dw_w, const float* __restrict__ dw_b,
    const float* __restrict__ bn1_g, const float* __restrict__ bn1_b,
    const float* __restrict__ bn1_m, const float* __restrict__ bn1_v,
    const float* __restrict__ pw_w, const float* __restrict__ pw_b,
    const float* __restrict__ bn2_g, const float* __restrict__ bn2_b,
    const float* __restrict__ bn2_m, const float* __restrict__ bn2_v,
    float* __restrict__ conv_out) {
    int bh = blockIdx.x;
    int b = bh / HH, h = bh % HH;
    __shared__ float row[WW * 97];        // [w][c] padded
    int t = threadIdx.x;
    for (int e = t; e < WW * CC; e += 256) {
        int w = e / CC, c = e % CC;
        float acc = dw_b[c];
        #pragma unroll
        for (int dy = -1; dy <= 1; ++dy) {
            int hh = h + dy; if (hh < 0 || hh >= HH) continue;
            #pragma unroll
            for (int dx = -1; dx <= 1; ++dx) {
                int ww = w + dx; if (ww < 0 || ww >= WW) continue;
                acc += x[((b * HH + hh) * WW + ww) * CC + c] * dw_w[c * 9 + (dy + 1) * 3 + (dx + 1)];
            }
        }
        float inv = rsqrtf(bn1_v[c] + 1e-5f);
        float v = (acc - bn1_m[c]) * inv * bn1_g[c] + bn1_b[c];
        row[w * 97 + c] = fmaxf(v, 0.f);
    }
    __syncthreads();
    int lane = t & 63;
    int wvu = __builtin_amdgcn_readfirstlane(t >> 6);   // uniform wave id
    if (lane < WW) {
        float acc[24];
        const float* pb = pw_b + wvu * 24;
        #pragma unroll
        for (int j = 0; j < 24; ++j) acc[j] = pb[j];
        const float* wb = pw_w + (wvu * 24) * CC;       // uniform base -> s_load
        for (int c = 0; c < CC; ++c) {
            float xv = row[lane * 97 + c];
            #pragma unroll
            for (int j = 0; j < 24; ++j)
                acc[j] += xv * wb[j * CC + c];
        }
        int o0 = wvu * 24;
        float* ob = conv_out + ((b * HH + h) * WW + lane) * CC + o0;
        #pragma unroll
        for (int j = 0; j < 24; ++j) {
            int o = o0 + j;
            float inv = rsqrtf(bn2_v[o] + 1e-5f);
            ob[j] = (acc[j] - bn2_m[o]) * inv * bn2_g[o] + bn2_b[o];
        }
    }
}

// ---------------- K2: LN + in_proj (tiled) -> xm_raw (B,192,L), z (B,192,L) -------------
__global__ __launch_bounds__(256) void k2_inproj(const float* __restrict__ x,
    const float* __restrict__ ln_g, const float* __restrict__ ln_b,
    const float* __restrict__ ipw,
    float* __restrict__ xm_raw, float* __restrict__ z_buf) {
    int t0 = blockIdx.x * 64;
    int og = blockIdx.y;
    int b = blockIdx.z;
    int lane = threadIdx.x & 63;
    int wv = threadIdx.x >> 6;
    int wvu = __builtin_amdgcn_readfirstlane(wv);
    __shared__ float xt[64 * 97];      // [p][c]
    __shared__ float xn[96 * 65];      // [c][p] normalized
    __shared__ float ps[4][64], ps2[4][64];
    const float* xb = x + (b * LL + t0) * CC;
    for (int e = threadIdx.x; e < 64 * CC; e += 256) {
        int p = e / CC, c = e % CC;
        xt[p * 97 + c] = xb[e];
    }
    __syncthreads();
    float s = 0.f, s2 = 0.f;
    #pragma unroll
    for (int j = 0; j < 24; ++j) {
        float v = xt[lane * 97 + wvu * 24 + j];
        s += v; s2 += v * v;
    }
    ps[wv][lane] = s; ps2[wv][lane] = s2;
    __syncthreads();
    float st = 0.f, st2 = 0.f;
    #pragma unroll
    for (int i = 0; i < 4; ++i) { st += ps[i][lane]; st2 += ps2[i][lane]; }
    float m = st * (1.f / 96.f);
    float inv = rsqrtf(st2 * (1.f / 96.f) - m * m + 1e-5f);
    #pragma unroll
    for (int j = 0; j < 24; ++j) {
        int c = wvu * 24 + j;
        xn[c * 65 + lane] = (xt[lane * 97 + c] - m) * inv * ln_g[c] + ln_b[c];
    }
    __syncthreads();
    float acc[24];
    #pragma unroll
    for (int j = 0; j < 24; ++j) acc[j] = 0.f;
    const float* wbase = ipw + (og * 96 + wvu * 24) * CC;   // uniform -> s_load
    for (int c = 0; c < CC; ++c) {
        float xv = xn[c * 65 + lane];
        #pragma unroll
        for (int j = 0; j < 24; ++j)
            acc[j] += xv * wbase[j * CC + c];
    }
    int p = t0 + lane;
    #pragma unroll
    for (int j = 0; j < 24; ++j) {
        int out = og * 96 + wvu * 24 + j;
        if (out < DI) xm_raw[(b * DI + out) * LL + p] = acc[j];
        else          z_buf[(b * DI + (out - DI)) * LL + p] = acc[j];
    }
}

// ---------------- K3: dwconv3 + SiLU -> v1 (row-major), v2 (col-major) ----------------
__global__ __launch_bounds__(256) void k3_dw(const float* __restrict__ xm_raw,
    const float* __restrict__ conv_w, const float* __restrict__ conv_b,
    float* __restrict__ v1, float* __restrict__ v2) {
    int bd = blockIdx.x;
    int d = bd % DI;
    __shared__ float tile[HH * 57];
    const float* src = xm_raw + bd * LL;
    float wloc[9];
    #pragma unroll
    for (int i = 0; i < 9; ++i) wloc[i] = conv_w[d * 9 + i];
    float bias = conv_b[d];
    for (int e = threadIdx.x; e < LL; e += 256) {
        int h = e / WW, w = e % WW;
        float acc = bias;
        #pragma unroll
        for (int dy = -1; dy <= 1; ++dy) {
            int hh = h + dy; if (hh < 0 || hh >= HH) continue;
            #pragma unroll
            for (int dx = -1; dx <= 1; ++dx) {
                int ww = w + dx; if (ww < 0 || ww >= WW) continue;
                acc += src[hh * WW + ww] * wloc[(dy + 1) * 3 + (dx + 1)];
            }
        }
        float sig = 1.f / (1.f + __expf(-acc));
        float v = acc * sig;
        v1[bd * LL + e] = v;
        tile[h * 57 + w] = v;
    }
    __syncthreads();
    for (int e = threadIdx.x; e < LL; e += 256) {
        int w = e / HH, h = e % HH;
        v2[bd * LL + e] = tile[h * 57 + w];
    }
}

// ---------------- K4: x_proj + dt_proj + softplus ----------------
// grid (NT, 4, BZ) x 256: one block per (64-pos tile, k, b). 10 rows/wave,
// wave-uniform weight bases via readfirstlane -> s_load.
__global__ __launch_bounds__(256) void k4_proj(const float* __restrict__ v1,
    const float* __restrict__ v2, const float* __restrict__ xpw,
    const float* __restrict__ dtw, const float* __restrict__ dtb,
    float* __restrict__ dt_s, float* __restrict__ B_s, float* __restrict__ C_s) {
    int t0 = blockIdx.x * 64;
    int k = blockIdx.y;
    int b = blockIdx.z;
    int lane = threadIdx.x & 63;
    int wvu = __builtin_amdgcn_readfirstlane(threadIdx.x >> 6);
    __shared__ float xs_l[DI * 64];
    __shared__ float dtr[RR * 64];
    const float* src = ((k & 1) == 0 ? v1 : v2) + b * DI * LL + t0;
    for (int e = threadIdx.x; e < DI * 64; e += 256) {
        int d = e >> 6, p = e & 63;
        xs_l[e] = src[d * LL + p];
    }
    __syncthreads();
    int r0 = wvu * 10; if (r0 > 28) r0 = 28;   // waves cover rows 0-9,10-19,20-29,28-37
    float acc[10];
    #pragma unroll
    for (int i = 0; i < 10; ++i) acc[i] = 0.f;
    const float* wbase = xpw + (k * 38 + r0) * DI;   // uniform -> s_load
    for (int d = 0; d < DI; ++d) {
        float xv = xs_l[d * 64 + lane];
        #pragma unroll
        for (int i = 0; i < 10; ++i)
            acc[i] += xv * wbase[i * DI + d];
    }
    int p = t0 + lane;
    #pragma unroll
    for (int i = 0; i < 10; ++i) {
        int c = r0 + i;
        if (c < RR) {
            dtr[c * 64 + lane] = acc[i];
        } else if (c < RR + NS) {
            B_s[((b * 4 + k) * NS + (c - RR)) * LL + p] = acc[i];
        } else {
            C_s[((b * 4 + k) * NS + (c - RR - NS)) * LL + p] = acc[i];
        }
    }
    __syncthreads();
    for (int i = 0; i < 48; ++i) {
        int d = wvu * 48 + i;                       // uniform
        float a = dtb[k * DI + d];
        const float* wr = dtw + (k * DI + d) * RR;  // uniform -> s_load
        #pragma unroll
        for (int r = 0; r < RR; ++r)
            a += dtr[r * 64 + lane] * wr[r];
        dt_s[((b * 4 + k) * DI + d) * LL + p] = softplusf(a);
    }
}

// ---------------- K5a: scan phase 1 — per-chunk local scan, lane = d ----------------
__global__ __launch_bounds__(64) void k5a_scan(float* __restrict__ dt_s,
    const float* __restrict__ B_s, const float* __restrict__ C_s,
    const float* __restrict__ v1, const float* __restrict__ v2,
    const float* __restrict__ A_logs, float* __restrict__ y_scan,
    float* __restrict__ hlast) {
    int bx = blockIdx.x;
    int dg = bx % 3, c = bx / 3;
    int k = blockIdx.y, b = blockIdx.z;
    int bk = b * 4 + k;
    int lane = threadIdx.x;
    int d0 = dg * 64, d = d0 + lane;
    bool fwd = (k < 2);
    int s0 = fwd ? c * 64 : (LL - (c + 1) * 64);
    __shared__ float dt_l[64 * 65];
    __shared__ float u_l[64 * 65];
    float Ae[16];
    const float* ap = A_logs + (k * DI + d) * NS;
    #pragma unroll
    for (int n = 0; n < 16; ++n) Ae[n] = -__expf(ap[n]) * 1.442695040888963f;
    const float* dtp = dt_s + (bk * DI + d0) * LL + s0;
    const float* up  = ((k == 0 || k == 2) ? v1 : v2) + (b * DI + d0) * LL + s0;
    #pragma unroll 8
    for (int r = 0; r < 64; ++r) {
        dt_l[r * 65 + lane] = dtp[r * LL + lane];
        u_l[r * 65 + lane]  = up[r * LL + lane];
    }
    __syncthreads();
    float h[16];
    #pragma unroll
    for (int n = 0; n < 16; ++n) h[n] = 0.f;
    float cum = 0.f;
    const float* Bb = B_s + (bk * NS) * LL + s0;
    const float* Cb = C_s + (bk * NS) * LL + s0;
    for (int jj = 0; jj < 64; ++jj) {
        int j = fwd ? jj : 63 - jj;
        float dtv = dt_l[lane * 65 + j];
        float uv  = u_l[lane * 65 + j];
        float du = dtv * uv;
        cum += dtv;
        float y = 0.f;
        #pragma unroll
        for (int n = 0; n < 16; ++n) {
            float bv = Bb[n * LL + j];
            float cv = Cb[n * LL + j];
            h[n] = exp2f(dtv * Ae[n]) * h[n] + du * bv;
            y += h[n] * cv;
        }
        u_l[lane * 65 + j] = y;
        dt_l[lane * 65 + j] = cum;
    }
    __syncthreads();
    float* yp = y_scan + (bk * DI + d0) * LL + s0;
    float* cp = dt_s + (bk * DI + d0) * LL + s0;
    #pragma unroll 8
    for (int r = 0; r < 64; ++r) {
        yp[r * LL + lane] = u_l[r * 65 + lane];
        cp[r * LL + lane] = dt_l[r * 65 + lane];
    }
    float4* hp4 = (float4*)(hlast + (bk * NC + c) * (DI * NS) + d * NS);
    hp4[0] = make_float4(h[0], h[1], h[2], h[3]);
    hp4[1] = make_float4(h[4], h[5], h[6], h[7]);
    hp4[2] = make_float4(h[8], h[9], h[10], h[11]);
    hp4[3] = make_float4(h[12], h[13], h[14], h[15]);
}

// ---------------- K5c: scan phase 2 — serial chunk combine ----------------
__global__ __launch_bounds__(64) void k5c_comb(const float* __restrict__ hlast,
    const float* __restrict__ cumdt, const float* __restrict__ negA,
    float* __restrict__ hin) {
    int dg = blockIdx.x, k = blockIdx.y, b = blockIdx.z;
    int lane = threadIdx.x, dl = lane >> 4, n = lane & 15;
    int d = dg * 4 + dl;
    int bk = b * 4 + k;
    bool fwd = (k < 2);
    float Av = negA[(k * DI + d) * NS + n];
    float H = 0.f;
    for (int c = 0; c < NC; ++c) {
        hin[(bk * NC + c) * (48 * 64) + dg * 64 + lane] = H;
        int s0 = fwd ? c * 64 : (LL - (c + 1) * 64);
        int jlast = fwd ? s0 + 63 : s0;
        float T = cumdt[(bk * DI + d) * LL + jlast];
        float hl = hlast[(bk * NC + c) * (48 * 64) + dg * 64 + lane];
        H = hl + __expf(Av * T) * H;
    }
}

// ---------------- K5d: scan phase 3 — parallel correction ----------------
__global__ __launch_bounds__(256) void k5d_corr(const float* __restrict__ cumdt,
    const float* __restrict__ C_s, const float* __restrict__ hin,
    const float* __restrict__ negA, float* __restrict__ y_scan) {
    int t = blockIdx.x;
    int k = blockIdx.y, b = blockIdx.z;
    bool fwd = (k < 2);
    int tile = fwd ? (t + 1) : t;
    int c = fwd ? tile : (48 - tile);
    int s0 = tile * 64;
    int lane = threadIdx.x & 63;
    int wvu = __builtin_amdgcn_readfirstlane(threadIdx.x >> 6);
    int bk = b * 4 + k;
    __shared__ float c_l[16 * 65];
    for (int e = threadIdx.x; e < 16 * 64; e += 256) {
        int n = e >> 6, s = e & 63;
        c_l[n * 65 + s] = C_s[(bk * NS + n) * LL + s0 + s];
    }
    __syncthreads();
    for (int dd = 0; dd < 48; ++dd) {
        int d = wvu * 48 + dd;                                   // uniform
        float cd = cumdt[(bk * DI + d) * LL + s0 + lane];
        const float* hp = hin + (bk * NC + c) * (48 * 64) + d * 16;  // uniform -> s_load
        const float* ap = negA + (k * DI + d) * NS;                  // uniform -> s_load
        float acc = 0.f;
        #pragma unroll
        for (int n = 0; n < 16; ++n) {
            acc += c_l[n * 65 + lane] * __expf(ap[n] * cd) * hp[n];
        }
        y_scan[(bk * DI + d) * LL + s0 + lane] += acc;
    }
}

// ---------------- K5b: transpose y for k=1,3 ----------------
__global__ __launch_bounds__(64) void k5b_tr(const float* __restrict__ y_scan,
                                             float* __restrict__ y13t) {
    int idx = blockIdx.x;
    int d = idx % DI;
    int bk = idx / DI;
    int kk = bk % 2, b = bk / 2;
    int k = (kk == 0) ? 1 : 3;
    __shared__ float tile[HH * 57];
    const float* src = y_scan + ((b * 4 + k) * DI + d) * LL;
    for (int e = threadIdx.x; e < LL; e += 64) {
        int w = e / HH, h = e % HH;
        tile[h * 57 + w] = src[e];
    }
    __syncthreads();
    float* dst = y13t + idx * LL;
    for (int e = threadIdx.x; e < LL; e += 64) {
        int h = e / WW, w = e % WW;
        dst[e] = tile[h * 57 + w];
    }
}

// ---------------- K6: gather 4 dirs + D*u + out_norm + silu(z) gate -> t ----------------
// grid (2*NT, BZ) x 256: 32-position tiles, 8 slices x 24 d's.
__global__ __launch_bounds__(256) void k6_gather(const float* __restrict__ y_scan,
    const float* __restrict__ y13t, const float* __restrict__ v1,
    const float* __restrict__ z_buf, const float* __restrict__ Ds,
    const float* __restrict__ ong, const float* __restrict__ onb,
    float* __restrict__ t_buf) {
    int t0 = blockIdx.x * 32;
    int b = blockIdx.y;
    int p32 = threadIdx.x & 31, sl = threadIdx.x >> 5;
    int p = t0 + p32;
    __shared__ float yv[DI * 33];
    __shared__ float ps[8][32], ps2[8][32];
    float s = 0.f, s2 = 0.f;
    for (int j = 0; j < 24; ++j) {
        int d = sl * 24 + j;
        float dsum = Ds[d] + Ds[DI + d] + Ds[2 * DI + d] + Ds[3 * DI + d];
        float val = y_scan[((b * 4 + 0) * DI + d) * LL + p]
                  + y_scan[((b * 4 + 2) * DI + d) * LL + p]
                  + y13t[((b * 2 + 0) * DI + d) * LL + p]
                  + y13t[((b * 2 + 1) * DI + d) * LL + p]
                  + v1[(b * DI + d) * LL + p] * dsum;
        yv[d * 33 + p32] = val;
        s += val; s2 += val * val;
    }
    ps[sl][p32] = s; ps2[sl][p32] = s2;
    __syncthreads();
    float st = 0.f, st2 = 0.f;
    #pragma unroll
    for (int i = 0; i < 8; ++i) { st += ps[i][p32]; st2 += ps2[i][p32]; }
    float m = st * (1.f / 192.f);
    float inv = rsqrtf(st2 * (1.f / 192.f) - m * m + 1e-5f);
    for (int j = 0; j < 24; ++j) {
        int d = sl * 24 + j;
        float val = (yv[d * 33 + p32] - m) * inv * ong[d] + onb[d];
        float zz = z_buf[(b * DI + d) * LL + p];
        float sig = 1.f / (1.f + __expf(-zz));
        t_buf[(b * DI + d) * LL + p] = val * zz * sig;
    }
}

// ---------------- K7a: fused matmul (conv_out | t@W2) + fus_b -> fusedT (B,96,L) --------
// grid (NT, 4, BZ) x 256: 24 outputs per block, 6 per wave, scalarized weights.
__global__ __launch_bounds__(256) void k7a_mm(const float* __restrict__ t_buf,
    const float* __restrict__ conv_out, const float* __restrict__ W2,
    const float* __restrict__ fus_w, const float* __restrict__ fus_b,
    float* __restrict__ fusedT) {
    int t0 = blockIdx.x * 64;
    int og = blockIdx.y;
    int b = blockIdx.z;
    int lane = threadIdx.x & 63;
    int wvu = __builtin_amdgcn_readfirstlane(threadIdx.x >> 6);
    __shared__ float ct[CC * 65];      // [c][p]
    const float* cb = conv_out + (b * LL + t0) * CC;
    for (int e = threadIdx.x; e < 64 * CC; e += 256) {
        int p = e / CC, c = e % CC;
        ct[c * 65 + p] = cb[e];
    }
    __syncthreads();
    int o0 = og * 24 + wvu * 6;
    float acc[6];
    #pragma unroll
    for (int j = 0; j < 6; ++j) acc[j] = fus_b[o0 + j];
    int p = t0 + lane;
    const float* w2 = W2 + o0 * DI;          // uniform -> s_load
    for (int d = 0; d < DI; ++d) {
        float tv = t_buf[(b * DI + d) * LL + p];
        #pragma unroll
        for (int j = 0; j < 6; ++j)
            acc[j] += tv * w2[j * DI + d];
    }
    const float* fw = fus_w + o0 * DI;       // uniform -> s_load (cols 0..95)
    for (int c = 0; c < CC; ++c) {
        float cv = ct[c * 65 + lane];
        #pragma unroll
        for (int j = 0; j < 6; ++j)
            acc[j] += cv * fw[j * DI + c];
    }
    #pragma unroll
    for (int j = 0; j < 6; ++j)
        fusedT[(b * CC + o0 + j) * LL + p] = acc[j];
}

// ---------------- K7b: LN + residual -> out ----------------
__global__ __launch_bounds__(256) void k7b_ln(const float* __restrict__ fusedT,
    const float* __restrict__ flg, const float* __restrict__ flb,
    const float* __restrict__ x, float* __restrict__ out) {
    int t0 = blockIdx.x * 64;
    int b = blockIdx.y;
    int lane = threadIdx.x & 63, wv = threadIdx.x >> 6;
    __shared__ float ft[CC * 65];      // [o][p]
    __shared__ float res[64 * 97];
    __shared__ float ps[4][64], ps2[4][64];
    for (int e = threadIdx.x; e < CC * 64; e += 256) {
        int o = e >> 6, p = e & 63;
        ft[o * 65 + p] = fusedT[(b * CC + o) * LL + t0 + p];
    }
    __syncthreads();
    float s = 0.f, s2 = 0.f;
    #pragma unroll
    for (int j = 0; j < 24; ++j) {
        float v = ft[(wv * 24 + j) * 65 + lane];
        s += v; s2 += v * v;
    }
    ps[wv][lane] = s; ps2[wv][lane] = s2;
    __syncthreads();
    float st = 0.f, st2 = 0.f;
    #pragma unroll
    for (int i = 0; i < 4; ++i) { st += ps[i][lane]; st2 += ps2[i][lane]; }
    float m = st * (1.f / 96.f);
    float inv = rsqrtf(st2 * (1.f / 96.f) - m * m + 1e-5f);
    #pragma unroll
    for (int j = 0; j < 24; ++j) {
        int o = wv * 24 + j;
        res[lane * 97 + o] = (ft[o * 65 + lane] - m) * inv * flg[o] + flb[o];
    }
    __syncthreads();
    const float* xb = x + (b * LL + t0) * CC;
    float* ob = out + (b * LL + t0) * CC;
    for (int e = threadIdx.x; e < 64 * CC; e += 256) {
        int pl = e / CC, o = e % CC;
        ob[e] = xb[e] + res[pl * 97 + o];
    }
}

extern "C" void kernel_launch(void* const* d_in, const int* in_sizes, int n_in,
                              void* d_out, int out_size, void* d_ws, size_t ws_size,
                              hipStream_t stream) {
    const float* x        = (const float*)d_in[0];
    const float* dw_w     = (const float*)d_in[1];
    const float* dw_b     = (const float*)d_in[2];
    const float* bn1_g    = (const float*)d_in[3];
    const float* bn1_b    = (const float*)d_in[4];
    const float* bn1_m    = (const float*)d_in[5];
    const float* bn1_v    = (const float*)d_in[6];
    const float* pw_w     = (const float*)d_in[7];
    const float* pw_b     = (const float*)d_in[8];
    const float* bn2_g    = (const float*)d_in[9];
    const float* bn2_b    = (const float*)d_in[10];
    const float* bn2_m    = (const float*)d_in[11];
    const float* bn2_v    = (const float*)d_in[12];
    const float* ln_g     = (const float*)d_in[13];
    const float* ln_b     = (const float*)d_in[14];
    const float* ipw      = (const float*)d_in[15];
    const float* conv_w   = (const float*)d_in[16];
    const float* conv_b   = (const float*)d_in[17];
    const float* xpw      = (const float*)d_in[18];
    const float* dtw      = (const float*)d_in[19];
    const float* dtb      = (const float*)d_in[20];
    const float* A_logs   = (const float*)d_in[21];
    const float* Ds       = (const float*)d_in[22];
    const float* ong      = (const float*)d_in[23];
    const float* onb      = (const float*)d_in[24];
    const float* opw      = (const float*)d_in[25];
    const float* fus_w    = (const float*)d_in[26];
    const float* fus_b    = (const float*)d_in[27];
    const float* flg      = (const float*)d_in[28];
    const float* flb      = (const float*)d_in[29];

    float* ws = (float*)d_ws;
    float* conv_out = ws + OFF_CONV;
    float* xm_raw   = ws + OFF_XMRAW;
    float* z_buf    = ws + OFF_Z;
    float* v1       = ws + OFF_V1;
    float* v2       = ws + OFF_V2;
    float* dt_s     = ws + OFF_DT;     // becomes cumdt after k5a (in place)
    float* B_s      = ws + OFF_BS;
    float* C_s      = ws + OFF_CS;
    float* y_scan   = ws + OFF_Y;
    float* y13t     = ws + OFF_Y13;
    float* t_buf    = ws + OFF_T;
    float* W2       = ws + OFF_W2;
    float* hlast    = xm_raw;          // alias: xm_raw dead after k3
    float* hin      = t_buf;           // alias: t_buf dead until k6
    float* negA     = B_s;             // alias: B_s dead after k5a (k0c runs after k5a)
    float* fusedT   = y13t;            // alias: y13t dead after k6
    float* out      = (float*)d_out;

    k0_w2<<<dim3((CC * DI + 63) / 64), dim3(64), 0, stream>>>(fus_w, opw, W2);
    k1_conv<<<dim3(BZ * HH), dim3(256), 0, stream>>>(x, dw_w, dw_b, bn1_g, bn1_b, bn1_m, bn1_v,
                                                     pw_w, pw_b, bn2_g, bn2_b, bn2_m, bn2_v, conv_out);
    k2_inproj<<<dim3(NT, 4, BZ), dim3(256), 0, stream>>>(x, ln_g, ln_b, ipw, xm_raw, z_buf);
    k3_dw<<<dim3(BZ * DI), dim3(256), 0, stream>>>(xm_raw, conv_w, conv_b, v1, v2);
    k4_proj<<<dim3(NT, 4, BZ), dim3(256), 0, stream>>>(v1, v2, xpw, dtw, dtb, dt_s, B_s, C_s);
    k5a_scan<<<dim3(3 * NC, 4, BZ), dim3(64), 0, stream>>>(dt_s, B_s, C_s, v1, v2, A_logs, y_scan, hlast);
    k0c_negA<<<dim3(48), dim3(256), 0, stream>>>(A_logs, negA);
    k5c_comb<<<dim3(48, 4, BZ), dim3(64), 0, stream>>>(hlast, dt_s, negA, hin);
    k5d_corr<<<dim3(48, 4, BZ), dim3(256), 0, stream>>>(dt_s, C_s, hin, negA, y_scan);
    k5b_tr<<<dim3(BZ * 2 * DI), dim3(64), 0, stream>>>(y_scan, y13t);
    k6_gather<<<dim3(2 * NT, BZ), dim3(256), 0, stream>>>(y_scan, y13t, v1, z_buf, Ds, ong, onb, t_buf);
    k7a_mm<<<dim3(NT, 4, BZ), dim3(256), 0, stream>>>(t_buf, conv_out, W2, fus_w, fus_b, fusedT);
    k7b_ln<<<dim3(NT, BZ), dim3(256), 0, stream>>>(fusedT, flg, flb, x, out);
}

// Round 6
// 380.951 us; speedup vs baseline: 3.4314x; 1.1575x over previous
//
#include <hip/hip_runtime.h>
#include <math.h>

// Problem constants
#define BZ 2
#define HH 56
#define WW 56
#define LL 3136      // 56*56
#define CC 96        // DIM
#define DI 192       // DINNER
#define NS 16        // DSTATE
#define RR 6         // DTRANK
#define NT 49        // LL/64
#define NC 49        // chunks for scan

// Workspace layout (floats)
#define OFF_CONV   0
#define OFF_XMRAW  602112
#define OFF_Z      1806336
#define OFF_V1     3010560
#define OFF_V2     4214784
#define OFF_DT     5419008
#define OFF_BS     10235904
#define OFF_CS     10637312
#define OFF_Y      11038720
#define OFF_Y13    15855616
#define OFF_T      18264064
#define OFF_W2     19468288
// total 19486720 floats = ~78 MB

__device__ __forceinline__ float softplusf(float x) {
    if (x > 20.f) return x;
    return log1pf(__expf(x));
}

// ---------------- K0: W2[o][d] = sum_j fus_w[o][96+j] * out_proj_w[j][d] ----------------
__global__ __launch_bounds__(64) void k0_w2(const float* __restrict__ fus_w,
                                            const float* __restrict__ opw,
                                            float* __restrict__ W2) {
    int i = blockIdx.x * 64 + threadIdx.x;
    if (i >= CC * DI) return;
    int o = i / DI, d = i % DI;
    float acc = 0.f;
    for (int j = 0; j < CC; ++j)
        acc += fus_w[o * DI + CC + j] * opw[j * DI + d];
    W2[i] = acc;
}

// ---------------- K0c: negA[k][d][n] = -exp(A_logs) ----------------
__global__ __launch_bounds__(256) void k0c_negA(const float* __restrict__ A_logs,
                                                float* __restrict__ negA) {
    int i = blockIdx.x * 256 + threadIdx.x;
    if (i < 4 * DI * NS) negA[i] = -__expf(A_logs[i]);
}

// ---------------- K1a: dwconv3 + bn1 + relu (elementwise, fully parallel) ----------------
__global__ __launch_bounds__(256) void k1a_dw(const float* __restrict__ x,
    const float* __restrict__ dw_w, const float* __restrict__ dw_b,
    const float* __restrict__ bn1_g, const float* __restrict__ bn1_b,
    const float* __restrict__ bn1_m, const float* __restrict__ bn1_v,
    float* __restrict__ cbuf) {
    int i = blockIdx.x * 256 + threadIdx.x;   // BZ*LL*CC = 602112
    if (i >= BZ * LL * CC) return;
    int c = i % CC;
    int bl = i / CC;
    int l = bl % LL, b = bl / LL;
    int h = l / WW, w = l % WW;
    float acc = dw_b[c];
    #pragma unroll
    for (int dy = -1; dy <= 1; ++dy) {
        int hh = h + dy; if (hh < 0 || hh >= HH) continue;
        #pragma unroll
        for (int dx = -1; dx <= 1; ++dx) {
            int ww = w + dx; if (ww < 0 || ww >= WW) continue;
            acc += x[((b * HH + hh) * WW + ww) * CC + c] * dw_w[c * 9 + (dy + 1) * 3 + (dx + 1)];
        }
    }
    float inv = rsqrtf(bn1_v[c] + 1e-5f);
    float v = (acc - bn1_m[c]) * inv * bn1_g[c] + bn1_b[c];
    cbuf[i] = fmaxf(v, 0.f);
}

// ---------------- K1b: 1x1 conv (pw) + bn2 -> conv_out (B,L,96) NHWC ----------------
__global__ __launch_bounds__(256) void k1b_pw(const float* __restrict__ cbuf,
    const float* __restrict__ pw_w, const float* __restrict__ pw_b,
    const float* __restrict__ bn2_g, const float* __restrict__ bn2_b,
    const float* __restrict__ bn2_m, const float* __restrict__ bn2_v,
    float* __restrict__ conv_out) {
    int t0 = blockIdx.x * 64;
    int b = blockIdx.y;
    int lane = threadIdx.x & 63;
    int wvu = __builtin_amdgcn_readfirstlane(threadIdx.x >> 6);
    __shared__ float ct[CC * 65];      // [c][p]
    __shared__ float res[64 * 97];
    const float* cb = cbuf + (b * LL + t0) * CC;
    for (int e = threadIdx.x; e < 64 * CC; e += 256) {
        int p = e / CC, c = e % CC;
        ct[c * 65 + p] = cb[e];
    }
    __syncthreads();
    float acc[24];
    const float* pb = pw_b + wvu * 24;
    #pragma unroll
    for (int j = 0; j < 24; ++j) acc[j] = pb[j];
    const float* wb = pw_w + (wvu * 24) * CC;       // uniform -> s_load
    for (int c = 0; c < CC; ++c) {
        float xv = ct[c * 65 + lane];
        #pragma unroll
        for (int j = 0; j < 24; ++j)
            acc[j] += xv * wb[j * CC + c];
    }
    #pragma unroll
    for (int j = 0; j < 24; ++j) {
        int o = wvu * 24 + j;
        float inv = rsqrtf(bn2_v[o] + 1e-5f);
        res[lane * 97 + o] = (acc[j] - bn2_m[o]) * inv * bn2_g[o] + bn2_b[o];
    }
    __syncthreads();
    float* ob = conv_out + (b * LL + t0) * CC;
    for (int e = threadIdx.x; e < 64 * CC; e += 256) {
        int pl = e / CC, o = e % CC;
        ob[e] = res[pl * 97 + o];
    }
}

// ---------------- K2: LN + in_proj (tiled) -> xm_raw (B,192,L), z (B,192,L) -------------
__global__ __launch_bounds__(256) void k2_inproj(const float* __restrict__ x,
    const float* __restrict__ ln_g, const float* __restrict__ ln_b,
    const float* __restrict__ ipw,
    float* __restrict__ xm_raw, float* __restrict__ z_buf) {
    int t0 = blockIdx.x * 64;
    int og = blockIdx.y;
    int b = blockIdx.z;
    int lane = threadIdx.x & 63;
    int wv = threadIdx.x >> 6;
    int wvu = __builtin_amdgcn_readfirstlane(wv);
    __shared__ float xt[64 * 97];      // [p][c]
    __shared__ float xn[96 * 65];      // [c][p] normalized
    __shared__ float ps[4][64], ps2[4][64];
    const float* xb = x + (b * LL + t0) * CC;
    for (int e = threadIdx.x; e < 64 * CC; e += 256) {
        int p = e / CC, c = e % CC;
        xt[p * 97 + c] = xb[e];
    }
    __syncthreads();
    float s = 0.f, s2 = 0.f;
    #pragma unroll
    for (int j = 0; j < 24; ++j) {
        float v = xt[lane * 97 + wvu * 24 + j];
        s += v; s2 += v * v;
    }
    ps[wv][lane] = s; ps2[wv][lane] = s2;
    __syncthreads();
    float st = 0.f, st2 = 0.f;
    #pragma unroll
    for (int i = 0; i < 4; ++i) { st += ps[i][lane]; st2 += ps2[i][lane]; }
    float m = st * (1.f / 96.f);
    float inv = rsqrtf(st2 * (1.f / 96.f) - m * m + 1e-5f);
    #pragma unroll
    for (int j = 0; j < 24; ++j) {
        int c = wvu * 24 + j;
        xn[c * 65 + lane] = (xt[lane * 97 + c] - m) * inv * ln_g[c] + ln_b[c];
    }
    __syncthreads();
    float acc[24];
    #pragma unroll
    for (int j = 0; j < 24; ++j) acc[j] = 0.f;
    const float* wbase = ipw + (og * 96 + wvu * 24) * CC;   // uniform -> s_load
    for (int c = 0; c < CC; ++c) {
        float xv = xn[c * 65 + lane];
        #pragma unroll
        for (int j = 0; j < 24; ++j)
            acc[j] += xv * wbase[j * CC + c];
    }
    int p = t0 + lane;
    #pragma unroll
    for (int j = 0; j < 24; ++j) {
        int out = og * 96 + wvu * 24 + j;
        if (out < DI) xm_raw[(b * DI + out) * LL + p] = acc[j];
        else          z_buf[(b * DI + (out - DI)) * LL + p] = acc[j];
    }
}

// ---------------- K3: dwconv3 + SiLU -> v1 (row-major), v2 (col-major) ----------------
// grid (BZ*DI, 2): half image (28 rows) per block.
__global__ __launch_bounds__(256) void k3_dw(const float* __restrict__ xm_raw,
    const float* __restrict__ conv_w, const float* __restrict__ conv_b,
    float* __restrict__ v1, float* __restrict__ v2) {
    int bd = blockIdx.x;
    int half = blockIdx.y;
    int d = bd % DI;
    int h0 = half * 28;
    __shared__ float tile[28 * 57];
    const float* src = xm_raw + bd * LL;
    float wloc[9];
    #pragma unroll
    for (int i = 0; i < 9; ++i) wloc[i] = conv_w[d * 9 + i];
    float bias = conv_b[d];
    for (int e = threadIdx.x; e < 28 * WW; e += 256) {
        int hl = e / WW, w = e % WW;
        int h = h0 + hl;
        float acc = bias;
        #pragma unroll
        for (int dy = -1; dy <= 1; ++dy) {
            int hh = h + dy; if (hh < 0 || hh >= HH) continue;
            #pragma unroll
            for (int dx = -1; dx <= 1; ++dx) {
                int ww = w + dx; if (ww < 0 || ww >= WW) continue;
                acc += src[hh * WW + ww] * wloc[(dy + 1) * 3 + (dx + 1)];
            }
        }
        float sig = 1.f / (1.f + __expf(-acc));
        float v = acc * sig;
        v1[bd * LL + h * WW + w] = v;
        tile[hl * 57 + w] = v;
    }
    __syncthreads();
    for (int e = threadIdx.x; e < 28 * WW; e += 256) {
        int w = e / 28, hl = e % 28;
        v2[bd * LL + w * HH + h0 + hl] = tile[hl * 57 + w];
    }
}

// ---------------- K4: x_proj + dt_proj + softplus ----------------
__global__ __launch_bounds__(256) void k4_proj(const float* __restrict__ v1,
    const float* __restrict__ v2, const float* __restrict__ xpw,
    const float* __restrict__ dtw, const float* __restrict__ dtb,
    float* __restrict__ dt_s, float* __restrict__ B_s, float* __restrict__ C_s) {
    int t0 = blockIdx.x * 64;
    int k = blockIdx.y;
    int b = blockIdx.z;
    int lane = threadIdx.x & 63;
    int wvu = __builtin_amdgcn_readfirstlane(threadIdx.x >> 6);
    __shared__ float xs_l[DI * 64];
    __shared__ float dtr[RR * 64];
    const float* src = ((k & 1) == 0 ? v1 : v2) + b * DI * LL + t0;
    for (int e = threadIdx.x; e < DI * 64; e += 256) {
        int d = e >> 6, p = e & 63;
        xs_l[e] = src[d * LL + p];
    }
    __syncthreads();
    int r0 = wvu * 10; if (r0 > 28) r0 = 28;
    float acc[10];
    #pragma unroll
    for (int i = 0; i < 10; ++i) acc[i] = 0.f;
    const float* wbase = xpw + (k * 38 + r0) * DI;   // uniform -> s_load
    for (int d = 0; d < DI; ++d) {
        float xv = xs_l[d * 64 + lane];
        #pragma unroll
        for (int i = 0; i < 10; ++i)
            acc[i] += xv * wbase[i * DI + d];
    }
    int p = t0 + lane;
    #pragma unroll
    for (int i = 0; i < 10; ++i) {
        int c = r0 + i;
        if (c < RR) {
            dtr[c * 64 + lane] = acc[i];
        } else if (c < RR + NS) {
            B_s[((b * 4 + k) * NS + (c - RR)) * LL + p] = acc[i];
        } else {
            C_s[((b * 4 + k) * NS + (c - RR - NS)) * LL + p] = acc[i];
        }
    }
    __syncthreads();
    for (int i = 0; i < 48; ++i) {
        int d = wvu * 48 + i;
        float a = dtb[k * DI + d];
        const float* wr = dtw + (k * DI + d) * RR;
        #pragma unroll
        for (int r = 0; r < RR; ++r)
            a += dtr[r * 64 + lane] * wr[r];
        dt_s[((b * 4 + k) * DI + d) * LL + p] = softplusf(a);
    }
}

// ---------------- K5a: scan phase 1 — per-chunk local scan, lane = d ----------------
// B/C staged into LDS transposed [pos][n] (pad 36, float4-aligned) -> per step
// 8 wave-uniform ds_read_b128 broadcasts instead of 32 latency-bound loads.
__global__ __launch_bounds__(64) void k5a_scan(float* __restrict__ dt_s,
    const float* __restrict__ B_s, const float* __restrict__ C_s,
    const float* __restrict__ v1, const float* __restrict__ v2,
    const float* __restrict__ A_logs, float* __restrict__ y_scan,
    float* __restrict__ hlast) {
    int bx = blockIdx.x;
    int dg = bx % 3, c = bx / 3;
    int k = blockIdx.y, b = blockIdx.z;
    int bk = b * 4 + k;
    int lane = threadIdx.x;
    int d0 = dg * 64, d = d0 + lane;
    bool fwd = (k < 2);
    int s0 = fwd ? c * 64 : (LL - (c + 1) * 64);
    __shared__ float dt_l[64 * 65];
    __shared__ float u_l[64 * 65];
    __shared__ float4 bc4[64 * 9];       // [pos][36 floats]: B 0..15, C 16..31, pad
    float* bc = (float*)bc4;
    float Ae[16];
    const float* ap = A_logs + (k * DI + d) * NS;
    #pragma unroll
    for (int n = 0; n < 16; ++n) Ae[n] = -__expf(ap[n]) * 1.442695040888963f;
    const float* dtp = dt_s + (bk * DI + d0) * LL + s0;
    const float* up  = ((k == 0 || k == 2) ? v1 : v2) + (b * DI + d0) * LL + s0;
    #pragma unroll 8
    for (int r = 0; r < 64; ++r) {
        dt_l[r * 65 + lane] = dtp[r * LL + lane];
        u_l[r * 65 + lane]  = up[r * LL + lane];
    }
    const float* Bb = B_s + (bk * NS) * LL + s0;
    const float* Cb = C_s + (bk * NS) * LL + s0;
    #pragma unroll
    for (int n = 0; n < 16; ++n) {
        bc[lane * 36 + n]      = Bb[n * LL + lane];
        bc[lane * 36 + 16 + n] = Cb[n * LL + lane];
    }
    __syncthreads();
    float h[16];
    #pragma unroll
    for (int n = 0; n < 16; ++n) h[n] = 0.f;
    float cum = 0.f;
    for (int jj = 0; jj < 64; ++jj) {
        int j = fwd ? jj : 63 - jj;
        float dtv = dt_l[lane * 65 + j];
        float uv  = u_l[lane * 65 + j];
        float du = dtv * uv;
        cum += dtv;
        const float4* row = (const float4*)&bc[j * 36];
        float4 b0 = row[0], b1 = row[1], b2 = row[2], b3 = row[3];
        float4 c0 = row[4], c1 = row[5], c2 = row[6], c3 = row[7];
        float bv[16] = {b0.x,b0.y,b0.z,b0.w, b1.x,b1.y,b1.z,b1.w,
                        b2.x,b2.y,b2.z,b2.w, b3.x,b3.y,b3.z,b3.w};
        float cv[16] = {c0.x,c0.y,c0.z,c0.w, c1.x,c1.y,c1.z,c1.w,
                        c2.x,c2.y,c2.z,c2.w, c3.x,c3.y,c3.z,c3.w};
        float y = 0.f;
        #pragma unroll
        for (int n = 0; n < 16; ++n) {
            h[n] = exp2f(dtv * Ae[n]) * h[n] + du * bv[n];
            y += h[n] * cv[n];
        }
        u_l[lane * 65 + j] = y;
        dt_l[lane * 65 + j] = cum;
    }
    __syncthreads();
    float* yp = y_scan + (bk * DI + d0) * LL + s0;
    float* cp = dt_s + (bk * DI + d0) * LL + s0;
    #pragma unroll 8
    for (int r = 0; r < 64; ++r) {
        yp[r * LL + lane] = u_l[r * 65 + lane];
        cp[r * LL + lane] = dt_l[r * 65 + lane];
    }
    float4* hp4 = (float4*)(hlast + (bk * NC + c) * (DI * NS) + d * NS);
    hp4[0] = make_float4(h[0], h[1], h[2], h[3]);
    hp4[1] = make_float4(h[4], h[5], h[6], h[7]);
    hp4[2] = make_float4(h[8], h[9], h[10], h[11]);
    hp4[3] = make_float4(h[12], h[13], h[14], h[15]);
}

// ---------------- K5c: scan phase 2 — serial chunk combine ----------------
__global__ __launch_bounds__(64) void k5c_comb(const float* __restrict__ hlast,
    const float* __restrict__ cumdt, const float* __restrict__ negA,
    float* __restrict__ hin) {
    int dg = blockIdx.x, k = blockIdx.y, b = blockIdx.z;
    int lane = threadIdx.x, dl = lane >> 4, n = lane & 15;
    int d = dg * 4 + dl;
    int bk = b * 4 + k;
    bool fwd = (k < 2);
    float Av = negA[(k * DI + d) * NS + n];
    float H = 0.f;
    for (int c = 0; c < NC; ++c) {
        hin[(bk * NC + c) * (48 * 64) + dg * 64 + lane] = H;
        int s0 = fwd ? c * 64 : (LL - (c + 1) * 64);
        int jlast = fwd ? s0 + 63 : s0;
        float T = cumdt[(bk * DI + d) * LL + jlast];
        float hl = hlast[(bk * NC + c) * (48 * 64) + dg * 64 + lane];
        H = hl + __expf(Av * T) * H;
    }
}

// ---------------- K5d: scan phase 3 — parallel correction ----------------
__global__ __launch_bounds__(256) void k5d_corr(const float* __restrict__ cumdt,
    const float* __restrict__ C_s, const float* __restrict__ hin,
    const float* __restrict__ negA, float* __restrict__ y_scan) {
    int t = blockIdx.x;
    int k = blockIdx.y, b = blockIdx.z;
    bool fwd = (k < 2);
    int tile = fwd ? (t + 1) : t;
    int c = fwd ? tile : (48 - tile);
    int s0 = tile * 64;
    int lane = threadIdx.x & 63;
    int wvu = __builtin_amdgcn_readfirstlane(threadIdx.x >> 6);
    int bk = b * 4 + k;
    __shared__ float c_l[16 * 65];
    for (int e = threadIdx.x; e < 16 * 64; e += 256) {
        int n = e >> 6, s = e & 63;
        c_l[n * 65 + s] = C_s[(bk * NS + n) * LL + s0 + s];
    }
    __syncthreads();
    for (int dd = 0; dd < 48; ++dd) {
        int d = wvu * 48 + dd;
        float cd = cumdt[(bk * DI + d) * LL + s0 + lane];
        const float* hp = hin + (bk * NC + c) * (48 * 64) + d * 16;
        const float* ap = negA + (k * DI + d) * NS;
        float acc = 0.f;
        #pragma unroll
        for (int n = 0; n < 16; ++n) {
            acc += c_l[n * 65 + lane] * __expf(ap[n] * cd) * hp[n];
        }
        y_scan[(bk * DI + d) * LL + s0 + lane] += acc;
    }
}

// ---------------- K5b: transpose y for k=1,3 ----------------
__global__ __launch_bounds__(64) void k5b_tr(const float* __restrict__ y_scan,
                                             float* __restrict__ y13t) {
    int idx = blockIdx.x;
    int d = idx % DI;
    int bk = idx / DI;
    int kk = bk % 2, b = bk / 2;
    int k = (kk == 0) ? 1 : 3;
    __shared__ float tile[HH * 57];
    const float* src = y_scan + ((b * 4 + k) * DI + d) * LL;
    for (int e = threadIdx.x; e < LL; e += 64) {
        int w = e / HH, h = e % HH;
        tile[h * 57 + w] = src[e];
    }
    __syncthreads();
    float* dst = y13t + idx * LL;
    for (int e = threadIdx.x; e < LL; e += 64) {
        int h = e / WW, w = e % WW;
        dst[e] = tile[h * 57 + w];
    }
}

// ---------------- K6: gather 4 dirs + D*u + out_norm + silu(z) gate -> t ----------------
__global__ __launch_bounds__(256) void k6_gather(const float* __restrict__ y_scan,
    const float* __restrict__ y13t, const float* __restrict__ v1,
    const float* __restrict__ z_buf, const float* __restrict__ Ds,
    const float* __restrict__ ong, const float* __restrict__ onb,
    float* __restrict__ t_buf) {
    int t0 = blockIdx.x * 32;
    int b = blockIdx.y;
    int p32 = threadIdx.x & 31, sl = threadIdx.x >> 5;
    int p = t0 + p32;
    __shared__ float yv[DI * 33];
    __shared__ float ps[8][32], ps2[8][32];
    float s = 0.f, s2 = 0.f;
    for (int j = 0; j < 24; ++j) {
        int d = sl * 24 + j;
        float dsum = Ds[d] + Ds[DI + d] + Ds[2 * DI + d] + Ds[3 * DI + d];
        float val = y_scan[((b * 4 + 0) * DI + d) * LL + p]
                  + y_scan[((b * 4 + 2) * DI + d) * LL + p]
                  + y13t[((b * 2 + 0) * DI + d) * LL + p]
                  + y13t[((b * 2 + 1) * DI + d) * LL + p]
                  + v1[(b * DI + d) * LL + p] * dsum;
        yv[d * 33 + p32] = val;
        s += val; s2 += val * val;
    }
    ps[sl][p32] = s; ps2[sl][p32] = s2;
    __syncthreads();
    float st = 0.f, st2 = 0.f;
    #pragma unroll
    for (int i = 0; i < 8; ++i) { st += ps[i][p32]; st2 += ps2[i][p32]; }
    float m = st * (1.f / 192.f);
    float inv = rsqrtf(st2 * (1.f / 192.f) - m * m + 1e-5f);
    for (int j = 0; j < 24; ++j) {
        int d = sl * 24 + j;
        float val = (yv[d * 33 + p32] - m) * inv * ong[d] + onb[d];
        float zz = z_buf[(b * DI + d) * LL + p];
        float sig = 1.f / (1.f + __expf(-zz));
        t_buf[(b * DI + d) * LL + p] = val * zz * sig;
    }
}

// ---------------- K7a: fused matmul (conv_out | t@W2) + fus_b -> fusedT (B,96,L) --------
__global__ __launch_bounds__(256) void k7a_mm(const float* __restrict__ t_buf,
    const float* __restrict__ conv_out, const float* __restrict__ W2,
    const float* __restrict__ fus_w, const float* __restrict__ fus_b,
    float* __restrict__ fusedT) {
    int t0 = blockIdx.x * 64;
    int og = blockIdx.y;
    int b = blockIdx.z;
    int lane = threadIdx.x & 63;
    int wvu = __builtin_amdgcn_readfirstlane(threadIdx.x >> 6);
    __shared__ float ct[CC * 65];      // [c][p]
    const float* cb = conv_out + (b * LL + t0) * CC;
    for (int e = threadIdx.x; e < 64 * CC; e += 256) {
        int p = e / CC, c = e % CC;
        ct[c * 65 + p] = cb[e];
    }
    __syncthreads();
    int o0 = og * 24 + wvu * 6;
    float acc[6];
    #pragma unroll
    for (int j = 0; j < 6; ++j) acc[j] = fus_b[o0 + j];
    int p = t0 + lane;
    const float* w2 = W2 + o0 * DI;          // uniform -> s_load
    for (int d = 0; d < DI; ++d) {
        float tv = t_buf[(b * DI + d) * LL + p];
        #pragma unroll
        for (int j = 0; j < 6; ++j)
            acc[j] += tv * w2[j * DI + d];
    }
    const float* fw = fus_w + o0 * DI;       // uniform -> s_load (cols 0..95)
    for (int c = 0; c < CC; ++c) {
        float cv = ct[c * 65 + lane];
        #pragma unroll
        for (int j = 0; j < 6; ++j)
            acc[j] += cv * fw[j * DI + c];
    }
    #pragma unroll
    for (int j = 0; j < 6; ++j)
        fusedT[(b * CC + o0 + j) * LL + p] = acc[j];
}

// ---------------- K7b: LN + residual -> out ----------------
__global__ __launch_bounds__(256) void k7b_ln(const float* __restrict__ fusedT,
    const float* __restrict__ flg, const float* __restrict__ flb,
    const float* __restrict__ x, float* __restrict__ out) {
    int t0 = blockIdx.x * 64;
    int b = blockIdx.y;
    int lane = threadIdx.x & 63, wv = threadIdx.x >> 6;
    __shared__ float ft[CC * 65];      // [o][p]
    __shared__ float res[64 * 97];
    __shared__ float ps[4][64], ps2[4][64];
    for (int e = threadIdx.x; e < CC * 64; e += 256) {
        int o = e >> 6, p = e & 63;
        ft[o * 65 + p] = fusedT[(b * CC + o) * LL + t0 + p];
    }
    __syncthreads();
    float s = 0.f, s2 = 0.f;
    #pragma unroll
    for (int j = 0; j < 24; ++j) {
        float v = ft[(wv * 24 + j) * 65 + lane];
        s += v; s2 += v * v;
    }
    ps[wv][lane] = s; ps2[wv][lane] = s2;
    __syncthreads();
    float st = 0.f, st2 = 0.f;
    #pragma unroll
    for (int i = 0; i < 4; ++i) { st += ps[i][lane]; st2 += ps2[i][lane]; }
    float m = st * (1.f / 96.f);
    float inv = rsqrtf(st2 * (1.f / 96.f) - m * m + 1e-5f);
    #pragma unroll
    for (int j = 0; j < 24; ++j) {
        int o = wv * 24 + j;
        res[lane * 97 + o] = (ft[o * 65 + lane] - m) * inv * flg[o] + flb[o];
    }
    __syncthreads();
    const float* xb = x + (b * LL + t0) * CC;
    float* ob = out + (b * LL + t0) * CC;
    for (int e = threadIdx.x; e < 64 * CC; e += 256) {
        int pl = e / CC, o = e % CC;
        ob[e] = xb[e] + res[pl * 97 + o];
    }
}

extern "C" void kernel_launch(void* const* d_in, const int* in_sizes, int n_in,
                              void* d_out, int out_size, void* d_ws, size_t ws_size,
                              hipStream_t stream) {
    const float* x        = (const float*)d_in[0];
    const float* dw_w     = (const float*)d_in[1];
    const float* dw_b     = (const float*)d_in[2];
    const float* bn1_g    = (const float*)d_in[3];
    const float* bn1_b    = (const float*)d_in[4];
    const float* bn1_m    = (const float*)d_in[5];
    const float* bn1_v    = (const float*)d_in[6];
    const float* pw_w     = (const float*)d_in[7];
    const float* pw_b     = (const float*)d_in[8];
    const float* bn2_g    = (const float*)d_in[9];
    const float* bn2_b    = (const float*)d_in[10];
    const float* bn2_m    = (const float*)d_in[11];
    const float* bn2_v    = (const float*)d_in[12];
    const float* ln_g     = (const float*)d_in[13];
    const float* ln_b     = (const float*)d_in[14];
    const float* ipw      = (const float*)d_in[15];
    const float* conv_w   = (const float*)d_in[16];
    const float* conv_b   = (const float*)d_in[17];
    const float* xpw      = (const float*)d_in[18];
    const float* dtw      = (const float*)d_in[19];
    const float* dtb      = (const float*)d_in[20];
    const float* A_logs   = (const float*)d_in[21];
    const float* Ds       = (const float*)d_in[22];
    const float* ong      = (const float*)d_in[23];
    const float* onb      = (const float*)d_in[24];
    const float* opw      = (const float*)d_in[25];
    const float* fus_w    = (const float*)d_in[26];
    const float* fus_b    = (const float*)d_in[27];
    const float* flg      = (const float*)d_in[28];
    const float* flb      = (const float*)d_in[29];

    float* ws = (float*)d_ws;
    float* conv_out = ws + OFF_CONV;
    float* xm_raw   = ws + OFF_XMRAW;
    float* z_buf    = ws + OFF_Z;
    float* v1       = ws + OFF_V1;
    float* v2       = ws + OFF_V2;
    float* dt_s     = ws + OFF_DT;     // becomes cumdt after k5a (in place)
    float* B_s      = ws + OFF_BS;
    float* C_s      = ws + OFF_CS;
    float* y_scan   = ws + OFF_Y;
    float* y13t     = ws + OFF_Y13;
    float* t_buf    = ws + OFF_T;
    float* W2       = ws + OFF_W2;
    float* hlast    = xm_raw;          // alias: xm_raw dead after k3
    float* hin      = t_buf;           // alias: t_buf dead until k6
    float* negA     = B_s;             // alias: B_s dead after k5a
    float* cbuf     = y13t;            // alias: y13t region free until k5b
    float* fusedT   = y13t;            // alias: y13t dead after k6
    float* out      = (float*)d_out;

    k0_w2<<<dim3((CC * DI + 63) / 64), dim3(64), 0, stream>>>(fus_w, opw, W2);
    k1a_dw<<<dim3((BZ * LL * CC + 255) / 256), dim3(256), 0, stream>>>(x, dw_w, dw_b,
                                                     bn1_g, bn1_b, bn1_m, bn1_v, cbuf);
    k1b_pw<<<dim3(NT, BZ), dim3(256), 0, stream>>>(cbuf, pw_w, pw_b,
                                                   bn2_g, bn2_b, bn2_m, bn2_v, conv_out);
    k2_inproj<<<dim3(NT, 4, BZ), dim3(256), 0, stream>>>(x, ln_g, ln_b, ipw, xm_raw, z_buf);
    k3_dw<<<dim3(BZ * DI, 2), dim3(256), 0, stream>>>(xm_raw, conv_w, conv_b, v1, v2);
    k4_proj<<<dim3(NT, 4, BZ), dim3(256), 0, stream>>>(v1, v2, xpw, dtw, dtb, dt_s, B_s, C_s);
    k5a_scan<<<dim3(3 * NC, 4, BZ), dim3(64), 0, stream>>>(dt_s, B_s, C_s, v1, v2, A_logs, y_scan, hlast);
    k0c_negA<<<dim3(48), dim3(256), 0, stream>>>(A_logs, negA);
    k5c_comb<<<dim3(48, 4, BZ), dim3(64), 0, stream>>>(hlast, dt_s, negA, hin);
    k5d_corr<<<dim3(48, 4, BZ), dim3(256), 0, stream>>>(dt_s, C_s, hin, negA, y_scan);
    k5b_tr<<<dim3(BZ * 2 * DI), dim3(64), 0, stream>>>(y_scan, y13t);
    k6_gather<<<dim3(2 * NT, BZ), dim3(256), 0, stream>>>(y_scan, y13t, v1, z_buf, Ds, ong, onb, t_buf);
    k7a_mm<<<dim3(NT, 4, BZ), dim3(256), 0, stream>>>(t_buf, conv_out, W2, fus_w, fus_b, fusedT);
    k7b_ln<<<dim3(NT, BZ), dim3(256), 0, stream>>>(fusedT, flg, flb, x, out);
}

// Round 7
// 371.991 us; speedup vs baseline: 3.5140x; 1.0241x over previous
//
#include <hip/hip_runtime.h>
#include <math.h>

// Problem constants
#define BZ 2
#define HH 56
#define WW 56
#define LL 3136      // 56*56
#define CC 96        // DIM
#define DI 192       // DINNER
#define NS 16        // DSTATE
#define RR 6         // DTRANK
#define NT 49        // LL/64
#define NCH 98       // scan chunks (32 positions each)
#define CH 32        // chunk length

// Workspace layout (floats)
#define OFF_CONV   0
#define OFF_XMRAW  602112
#define OFF_Z      1806336
#define OFF_V1     3010560
#define OFF_V2     4214784
#define OFF_DT     5419008
#define OFF_BS     10235904
#define OFF_CS     10637312
#define OFF_Y      11038720
#define OFF_Y13    15855616
#define OFF_T      18264064
#define OFF_W2     19468288
// total 19486720 floats = ~78 MB

__device__ __forceinline__ float softplusf(float x) {
    if (x > 20.f) return x;
    return log1pf(__expf(x));
}

// ---------------- K0: W2[o][d] = sum_j fus_w[o][96+j] * out_proj_w[j][d] ----------------
__global__ __launch_bounds__(64) void k0_w2(const float* __restrict__ fus_w,
                                            const float* __restrict__ opw,
                                            float* __restrict__ W2) {
    int i = blockIdx.x * 64 + threadIdx.x;
    if (i >= CC * DI) return;
    int o = i / DI, d = i % DI;
    float acc = 0.f;
    for (int j = 0; j < CC; ++j)
        acc += fus_w[o * DI + CC + j] * opw[j * DI + d];
    W2[i] = acc;
}

// ---------------- K0c: negA[k][d][n] = -exp(A_logs) ----------------
__global__ __launch_bounds__(256) void k0c_negA(const float* __restrict__ A_logs,
                                                float* __restrict__ negA) {
    int i = blockIdx.x * 256 + threadIdx.x;
    if (i < 4 * DI * NS) negA[i] = -__expf(A_logs[i]);
}

// ---------------- K1a: dwconv3 + bn1 + relu (elementwise, fully parallel) ----------------
__global__ __launch_bounds__(256) void k1a_dw(const float* __restrict__ x,
    const float* __restrict__ dw_w, const float* __restrict__ dw_b,
    const float* __restrict__ bn1_g, const float* __restrict__ bn1_b,
    const float* __restrict__ bn1_m, const float* __restrict__ bn1_v,
    float* __restrict__ cbuf) {
    int i = blockIdx.x * 256 + threadIdx.x;
    if (i >= BZ * LL * CC) return;
    int c = i % CC;
    int bl = i / CC;
    int l = bl % LL, b = bl / LL;
    int h = l / WW, w = l % WW;
    float acc = dw_b[c];
    #pragma unroll
    for (int dy = -1; dy <= 1; ++dy) {
        int hh = h + dy; if (hh < 0 || hh >= HH) continue;
        #pragma unroll
        for (int dx = -1; dx <= 1; ++dx) {
            int ww = w + dx; if (ww < 0 || ww >= WW) continue;
            acc += x[((b * HH + hh) * WW + ww) * CC + c] * dw_w[c * 9 + (dy + 1) * 3 + (dx + 1)];
        }
    }
    float inv = rsqrtf(bn1_v[c] + 1e-5f);
    float v = (acc - bn1_m[c]) * inv * bn1_g[c] + bn1_b[c];
    cbuf[i] = fmaxf(v, 0.f);
}

// ---------------- K1b: 1x1 conv (pw) + bn2 -> conv_out (B,L,96) NHWC ----------------
__global__ __launch_bounds__(256) void k1b_pw(const float* __restrict__ cbuf,
    const float* __restrict__ pw_w, const float* __restrict__ pw_b,
    const float* __restrict__ bn2_g, const float* __restrict__ bn2_b,
    const float* __restrict__ bn2_m, const float* __restrict__ bn2_v,
    float* __restrict__ conv_out) {
    int t0 = blockIdx.x * 64;
    int b = blockIdx.y;
    int lane = threadIdx.x & 63;
    int wvu = __builtin_amdgcn_readfirstlane(threadIdx.x >> 6);
    __shared__ float ct[CC * 65];      // [c][p]
    __shared__ float res[64 * 97];
    const float* cb = cbuf + (b * LL + t0) * CC;
    for (int e = threadIdx.x; e < 64 * CC; e += 256) {
        int p = e / CC, c = e % CC;
        ct[c * 65 + p] = cb[e];
    }
    __syncthreads();
    float acc[24];
    const float* pb = pw_b + wvu * 24;
    #pragma unroll
    for (int j = 0; j < 24; ++j) acc[j] = pb[j];
    const float* wb = pw_w + (wvu * 24) * CC;       // uniform -> s_load
    for (int c = 0; c < CC; ++c) {
        float xv = ct[c * 65 + lane];
        #pragma unroll
        for (int j = 0; j < 24; ++j)
            acc[j] += xv * wb[j * CC + c];
    }
    #pragma unroll
    for (int j = 0; j < 24; ++j) {
        int o = wvu * 24 + j;
        float inv = rsqrtf(bn2_v[o] + 1e-5f);
        res[lane * 97 + o] = (acc[j] - bn2_m[o]) * inv * bn2_g[o] + bn2_b[o];
    }
    __syncthreads();
    float* ob = conv_out + (b * LL + t0) * CC;
    for (int e = threadIdx.x; e < 64 * CC; e += 256) {
        int pl = e / CC, o = e % CC;
        ob[e] = res[pl * 97 + o];
    }
}

// ---------------- K2: LN + in_proj (tiled) -> xm_raw (B,192,L), z (B,192,L) -------------
__global__ __launch_bounds__(256) void k2_inproj(const float* __restrict__ x,
    const float* __restrict__ ln_g, const float* __restrict__ ln_b,
    const float* __restrict__ ipw,
    float* __restrict__ xm_raw, float* __restrict__ z_buf) {
    int t0 = blockIdx.x * 64;
    int og = blockIdx.y;
    int b = blockIdx.z;
    int lane = threadIdx.x & 63;
    int wv = threadIdx.x >> 6;
    int wvu = __builtin_amdgcn_readfirstlane(wv);
    __shared__ float xt[64 * 97];      // [p][c]
    __shared__ float xn[96 * 65];      // [c][p] normalized
    __shared__ float ps[4][64], ps2[4][64];
    const float* xb = x + (b * LL + t0) * CC;
    for (int e = threadIdx.x; e < 64 * CC; e += 256) {
        int p = e / CC, c = e % CC;
        xt[p * 97 + c] = xb[e];
    }
    __syncthreads();
    float s = 0.f, s2 = 0.f;
    #pragma unroll
    for (int j = 0; j < 24; ++j) {
        float v = xt[lane * 97 + wvu * 24 + j];
        s += v; s2 += v * v;
    }
    ps[wv][lane] = s; ps2[wv][lane] = s2;
    __syncthreads();
    float st = 0.f, st2 = 0.f;
    #pragma unroll
    for (int i = 0; i < 4; ++i) { st += ps[i][lane]; st2 += ps2[i][lane]; }
    float m = st * (1.f / 96.f);
    float inv = rsqrtf(st2 * (1.f / 96.f) - m * m + 1e-5f);
    #pragma unroll
    for (int j = 0; j < 24; ++j) {
        int c = wvu * 24 + j;
        xn[c * 65 + lane] = (xt[lane * 97 + c] - m) * inv * ln_g[c] + ln_b[c];
    }
    __syncthreads();
    float acc[24];
    #pragma unroll
    for (int j = 0; j < 24; ++j) acc[j] = 0.f;
    const float* wbase = ipw + (og * 96 + wvu * 24) * CC;   // uniform -> s_load
    for (int c = 0; c < CC; ++c) {
        float xv = xn[c * 65 + lane];
        #pragma unroll
        for (int j = 0; j < 24; ++j)
            acc[j] += xv * wbase[j * CC + c];
    }
    int p = t0 + lane;
    #pragma unroll
    for (int j = 0; j < 24; ++j) {
        int out = og * 96 + wvu * 24 + j;
        if (out < DI) xm_raw[(b * DI + out) * LL + p] = acc[j];
        else          z_buf[(b * DI + (out - DI)) * LL + p] = acc[j];
    }
}

// ---------------- K3: dwconv3 + SiLU -> v1 (row-major), v2 (col-major) ----------------
__global__ __launch_bounds__(256) void k3_dw(const float* __restrict__ xm_raw,
    const float* __restrict__ conv_w, const float* __restrict__ conv_b,
    float* __restrict__ v1, float* __restrict__ v2) {
    int bd = blockIdx.x;
    int half = blockIdx.y;
    int d = bd % DI;
    int h0 = half * 28;
    __shared__ float tile[28 * 57];
    const float* src = xm_raw + bd * LL;
    float wloc[9];
    #pragma unroll
    for (int i = 0; i < 9; ++i) wloc[i] = conv_w[d * 9 + i];
    float bias = conv_b[d];
    for (int e = threadIdx.x; e < 28 * WW; e += 256) {
        int hl = e / WW, w = e % WW;
        int h = h0 + hl;
        float acc = bias;
        #pragma unroll
        for (int dy = -1; dy <= 1; ++dy) {
            int hh = h + dy; if (hh < 0 || hh >= HH) continue;
            #pragma unroll
            for (int dx = -1; dx <= 1; ++dx) {
                int ww = w + dx; if (ww < 0 || ww >= WW) continue;
                acc += src[hh * WW + ww] * wloc[(dy + 1) * 3 + (dx + 1)];
            }
        }
        float sig = 1.f / (1.f + __expf(-acc));
        float v = acc * sig;
        v1[bd * LL + h * WW + w] = v;
        tile[hl * 57 + w] = v;
    }
    __syncthreads();
    for (int e = threadIdx.x; e < 28 * WW; e += 256) {
        int w = e / 28, hl = e % 28;
        v2[bd * LL + w * HH + h0 + hl] = tile[hl * 57 + w];
    }
}

// ---------------- K4: x_proj + dt_proj + softplus ----------------
__global__ __launch_bounds__(256) void k4_proj(const float* __restrict__ v1,
    const float* __restrict__ v2, const float* __restrict__ xpw,
    const float* __restrict__ dtw, const float* __restrict__ dtb,
    float* __restrict__ dt_s, float* __restrict__ B_s, float* __restrict__ C_s) {
    int t0 = blockIdx.x * 64;
    int k = blockIdx.y;
    int b = blockIdx.z;
    int lane = threadIdx.x & 63;
    int wvu = __builtin_amdgcn_readfirstlane(threadIdx.x >> 6);
    __shared__ float xs_l[DI * 64];
    __shared__ float dtr[RR * 64];
    const float* src = ((k & 1) == 0 ? v1 : v2) + b * DI * LL + t0;
    for (int e = threadIdx.x; e < DI * 64; e += 256) {
        int d = e >> 6, p = e & 63;
        xs_l[e] = src[d * LL + p];
    }
    __syncthreads();
    int r0 = wvu * 10; if (r0 > 28) r0 = 28;
    float acc[10];
    #pragma unroll
    for (int i = 0; i < 10; ++i) acc[i] = 0.f;
    const float* wbase = xpw + (k * 38 + r0) * DI;   // uniform -> s_load
    for (int d = 0; d < DI; ++d) {
        float xv = xs_l[d * 64 + lane];
        #pragma unroll
        for (int i = 0; i < 10; ++i)
            acc[i] += xv * wbase[i * DI + d];
    }
    int p = t0 + lane;
    #pragma unroll
    for (int i = 0; i < 10; ++i) {
        int c = r0 + i;
        if (c < RR) {
            dtr[c * 64 + lane] = acc[i];
        } else if (c < RR + NS) {
            B_s[((b * 4 + k) * NS + (c - RR)) * LL + p] = acc[i];
        } else {
            C_s[((b * 4 + k) * NS + (c - RR - NS)) * LL + p] = acc[i];
        }
    }
    __syncthreads();
    for (int i = 0; i < 48; ++i) {
        int d = wvu * 48 + i;
        float a = dtb[k * DI + d];
        const float* wr = dtw + (k * DI + d) * RR;
        #pragma unroll
        for (int r = 0; r < RR; ++r)
            a += dtr[r * 64 + lane] * wr[r];
        dt_s[((b * 4 + k) * DI + d) * LL + p] = softplusf(a);
    }
}

// ---------------- K5a: scan phase 1 — 32-pos chunks, lane = d ----------------
// grid (3*NCH, 4, BZ) x 64. LDS = 21.5 KB -> ~7 blocks/CU.
// Outputs: local y, hlast (chunk-final states), Tbuf (chunk dt totals).
// No cumdt materialization (k5d reconstructs via shfl prefix).
__global__ __launch_bounds__(64) void k5a_scan(const float* __restrict__ dt_s,
    const float* __restrict__ B_s, const float* __restrict__ C_s,
    const float* __restrict__ v1, const float* __restrict__ v2,
    const float* __restrict__ A_logs, float* __restrict__ y_scan,
    float* __restrict__ hl_buf, float* __restrict__ Tbuf) {
    int bx = blockIdx.x;
    int dg = bx % 3, c = bx / 3;
    int k = blockIdx.y, b = blockIdx.z;
    int bk = b * 4 + k;
    int lane = threadIdx.x;
    int d0 = dg * 64, d = d0 + lane;
    bool fwd = (k < 2);
    int s0 = fwd ? c * CH : (LL - (c + 1) * CH);
    __shared__ float dtl[64 * 33];
    __shared__ float ul[64 * 33];
    __shared__ float bc[CH * 36];        // [pos][36]: B 0..15, C 16..31, pad
    float Ae[16];
    const float* ap = A_logs + (k * DI + d) * NS;
    #pragma unroll
    for (int n = 0; n < 16; ++n) Ae[n] = -__expf(ap[n]) * 1.442695040888963f;
    const float* dtp = dt_s + (bk * DI + d0) * LL + s0;
    const float* up  = ((k & 1) == 0 ? v1 : v2) + (b * DI + d0) * LL + s0;
    int pr = lane >> 5, pc = lane & 31;
    #pragma unroll 8
    for (int i = 0; i < 32; ++i) {
        int row = i * 2 + pr;
        dtl[row * 33 + pc] = dtp[row * LL + pc];
        ul[row * 33 + pc]  = up[row * LL + pc];
    }
    #pragma unroll
    for (int i = 0; i < 8; ++i) {
        int nn = i * 2 + pr;
        bc[pc * 36 + nn]      = B_s[(bk * NS + nn) * LL + s0 + pc];
        bc[pc * 36 + 16 + nn] = C_s[(bk * NS + nn) * LL + s0 + pc];
    }
    __syncthreads();
    float h[16];
    #pragma unroll
    for (int n = 0; n < 16; ++n) h[n] = 0.f;
    float cum = 0.f;
    for (int jj = 0; jj < CH; ++jj) {
        int j = fwd ? jj : CH - 1 - jj;
        float dtv = dtl[lane * 33 + j];
        float uv  = ul[lane * 33 + j];
        float du = dtv * uv;
        cum += dtv;
        const float4* row4 = (const float4*)&bc[j * 36];
        float4 b0 = row4[0], b1 = row4[1], b2 = row4[2], b3 = row4[3];
        float4 c0 = row4[4], c1 = row4[5], c2 = row4[6], c3 = row4[7];
        float bv[16] = {b0.x,b0.y,b0.z,b0.w, b1.x,b1.y,b1.z,b1.w,
                        b2.x,b2.y,b2.z,b2.w, b3.x,b3.y,b3.z,b3.w};
        float cv[16] = {c0.x,c0.y,c0.z,c0.w, c1.x,c1.y,c1.z,c1.w,
                        c2.x,c2.y,c2.z,c2.w, c3.x,c3.y,c3.z,c3.w};
        float y = 0.f;
        #pragma unroll
        for (int n = 0; n < 16; ++n) {
            h[n] = exp2f(dtv * Ae[n]) * h[n] + du * bv[n];
            y += h[n] * cv[n];
        }
        ul[lane * 33 + j] = y;
    }
    __syncthreads();
    float* yp = y_scan + (bk * DI + d0) * LL + s0;
    #pragma unroll 8
    for (int i = 0; i < 32; ++i) {
        int row = i * 2 + pr;
        yp[row * LL + pc] = ul[row * 33 + pc];
    }
    float4* hp4 = (float4*)(hl_buf + (bk * NCH + c) * (DI * NS) + d * NS);
    hp4[0] = make_float4(h[0], h[1], h[2], h[3]);
    hp4[1] = make_float4(h[4], h[5], h[6], h[7]);
    hp4[2] = make_float4(h[8], h[9], h[10], h[11]);
    hp4[3] = make_float4(h[12], h[13], h[14], h[15]);
    Tbuf[(bk * NCH + c) * DI + d] = cum;
}

// ---------------- K5c: scan phase 2 — serial chunk combine, IN PLACE ----------------
// hl_buf[c] (chunk-local final states) is replaced by hin[c] (state entering chunk c).
__global__ __launch_bounds__(64) void k5c_comb(float* __restrict__ hl_buf,
    const float* __restrict__ Tbuf, const float* __restrict__ negA) {
    int dg = blockIdx.x, k = blockIdx.y, b = blockIdx.z;
    int lane = threadIdx.x, dl = lane >> 4, n = lane & 15;
    int d = dg * 4 + dl;
    int bk = b * 4 + k;
    float Av = negA[(k * DI + d) * NS + n];
    float H = 0.f;
    for (int c = 0; c < NCH; ++c) {
        float* slot = hl_buf + (bk * NCH + c) * (DI * NS) + dg * 64 + lane;
        float hl = *slot;
        *slot = H;
        float T = Tbuf[(bk * NCH + c) * DI + d];
        H = hl + __expf(Av * T) * H;
    }
}

// ---------------- K5d: scan phase 3 — parallel correction (prefix via shfl) ----------
// grid (NCH-1, 4, BZ) x 256.  8 slices x 32 positions; cum rebuilt from dt_s.
__global__ __launch_bounds__(256) void k5d_corr(const float* __restrict__ dt_s,
    const float* __restrict__ C_s, const float* __restrict__ hin,
    const float* __restrict__ negA, float* __restrict__ y_scan) {
    int t = blockIdx.x;
    int k = blockIdx.y, b = blockIdx.z;
    bool fwd = (k < 2);
    int c  = fwd ? (t + 1) : (NCH - 1 - t);
    int s0 = fwd ? (t + 1) * CH : t * CH;
    int p32 = threadIdx.x & 31, sl = threadIdx.x >> 5;
    int bk = b * 4 + k;
    __shared__ float c_l[16 * 33];
    for (int e = threadIdx.x; e < 16 * CH; e += 256) {
        int n = e >> 5, s = e & 31;
        c_l[n * 33 + s] = C_s[(bk * NS + n) * LL + s0 + s];
    }
    __syncthreads();
    for (int j = 0; j < 24; ++j) {
        int d = sl * 24 + j;
        float dtv = dt_s[(bk * DI + d) * LL + s0 + p32];
        float cum = dtv;
        if (fwd) {
            #pragma unroll
            for (int off = 1; off < 32; off <<= 1) {
                float o = __shfl_up(cum, off, 32);
                if (p32 >= off) cum += o;
            }
        } else {
            #pragma unroll
            for (int off = 1; off < 32; off <<= 1) {
                float o = __shfl_down(cum, off, 32);
                if (p32 < 32 - off) cum += o;
            }
        }
        const float* hp = hin + (bk * NCH + c) * (DI * NS) + d * 16;
        const float* ap = negA + (k * DI + d) * NS;
        float acc = 0.f;
        #pragma unroll
        for (int n = 0; n < 16; ++n) {
            acc += c_l[n * 33 + p32] * __expf(ap[n] * cum) * hp[n];
        }
        y_scan[(bk * DI + d) * LL + s0 + p32] += acc;
    }
}

// ---------------- K5b: transpose y for k=1,3 ----------------
__global__ __launch_bounds__(256) void k5b_tr(const float* __restrict__ y_scan,
                                              float* __restrict__ y13t) {
    int idx = blockIdx.x;
    int d = idx % DI;
    int bk = idx / DI;
    int kk = bk % 2, b = bk / 2;
    int k = (kk == 0) ? 1 : 3;
    __shared__ float tile[HH * 57];
    const float* src = y_scan + ((b * 4 + k) * DI + d) * LL;
    for (int e = threadIdx.x; e < LL; e += 256) {
        int w = e / HH, h = e % HH;
        tile[h * 57 + w] = src[e];
    }
    __syncthreads();
    float* dst = y13t + idx * LL;
    for (int e = threadIdx.x; e < LL; e += 256) {
        int h = e / WW, w = e % WW;
        dst[e] = tile[h * 57 + w];
    }
}

// ---------------- K6: gather 4 dirs + D*u + out_norm + silu(z) gate -> t ----------------
__global__ __launch_bounds__(256) void k6_gather(const float* __restrict__ y_scan,
    const float* __restrict__ y13t, const float* __restrict__ v1,
    const float* __restrict__ z_buf, const float* __restrict__ Ds,
    const float* __restrict__ ong, const float* __restrict__ onb,
    float* __restrict__ t_buf) {
    int t0 = blockIdx.x * 32;
    int b = blockIdx.y;
    int p32 = threadIdx.x & 31, sl = threadIdx.x >> 5;
    int p = t0 + p32;
    __shared__ float yv[DI * 33];
    __shared__ float ps[8][32], ps2[8][32];
    float s = 0.f, s2 = 0.f;
    for (int j = 0; j < 24; ++j) {
        int d = sl * 24 + j;
        float dsum = Ds[d] + Ds[DI + d] + Ds[2 * DI + d] + Ds[3 * DI + d];
        float val = y_scan[((b * 4 + 0) * DI + d) * LL + p]
                  + y_scan[((b * 4 + 2) * DI + d) * LL + p]
                  + y13t[((b * 2 + 0) * DI + d) * LL + p]
                  + y13t[((b * 2 + 1) * DI + d) * LL + p]
                  + v1[(b * DI + d) * LL + p] * dsum;
        yv[d * 33 + p32] = val;
        s += val; s2 += val * val;
    }
    ps[sl][p32] = s; ps2[sl][p32] = s2;
    __syncthreads();
    float st = 0.f, st2 = 0.f;
    #pragma unroll
    for (int i = 0; i < 8; ++i) { st += ps[i][p32]; st2 += ps2[i][p32]; }
    float m = st * (1.f / 192.f);
    float inv = rsqrtf(st2 * (1.f / 192.f) - m * m + 1e-5f);
    for (int j = 0; j < 24; ++j) {
        int d = sl * 24 + j;
        float val = (yv[d * 33 + p32] - m) * inv * ong[d] + onb[d];
        float zz = z_buf[(b * DI + d) * LL + p];
        float sig = 1.f / (1.f + __expf(-zz));
        t_buf[(b * DI + d) * LL + p] = val * zz * sig;
    }
}

// ---------------- K7a: fused matmul (conv_out | t@W2) + fus_b -> fusedT (B,96,L) --------
__global__ __launch_bounds__(256) void k7a_mm(const float* __restrict__ t_buf,
    const float* __restrict__ conv_out, const float* __restrict__ W2,
    const float* __restrict__ fus_w, const float* __restrict__ fus_b,
    float* __restrict__ fusedT) {
    int t0 = blockIdx.x * 64;
    int og = blockIdx.y;
    int b = blockIdx.z;
    int lane = threadIdx.x & 63;
    int wvu = __builtin_amdgcn_readfirstlane(threadIdx.x >> 6);
    __shared__ float ct[CC * 65];      // [c][p]
    const float* cb = conv_out + (b * LL + t0) * CC;
    for (int e = threadIdx.x; e < 64 * CC; e += 256) {
        int p = e / CC, c = e % CC;
        ct[c * 65 + p] = cb[e];
    }
    __syncthreads();
    int o0 = og * 24 + wvu * 6;
    float acc[6];
    #pragma unroll
    for (int j = 0; j < 6; ++j) acc[j] = fus_b[o0 + j];
    int p = t0 + lane;
    const float* w2 = W2 + o0 * DI;          // uniform -> s_load
    for (int d = 0; d < DI; ++d) {
        float tv = t_buf[(b * DI + d) * LL + p];
        #pragma unroll
        for (int j = 0; j < 6; ++j)
            acc[j] += tv * w2[j * DI + d];
    }
    const float* fw = fus_w + o0 * DI;       // uniform -> s_load (cols 0..95)
    for (int c = 0; c < CC; ++c) {
        float cv = ct[c * 65 + lane];
        #pragma unroll
        for (int j = 0; j < 6; ++j)
            acc[j] += cv * fw[j * DI + c];
    }
    #pragma unroll
    for (int j = 0; j < 6; ++j)
        fusedT[(b * CC + o0 + j) * LL + p] = acc[j];
}

// ---------------- K7b: LN + residual -> out ----------------
__global__ __launch_bounds__(256) void k7b_ln(const float* __restrict__ fusedT,
    const float* __restrict__ flg, const float* __restrict__ flb,
    const float* __restrict__ x, float* __restrict__ out) {
    int t0 = blockIdx.x * 64;
    int b = blockIdx.y;
    int lane = threadIdx.x & 63, wv = threadIdx.x >> 6;
    __shared__ float ft[CC * 65];      // [o][p]
    __shared__ float res[64 * 97];
    __shared__ float ps[4][64], ps2[4][64];
    for (int e = threadIdx.x; e < CC * 64; e += 256) {
        int o = e >> 6, p = e & 63;
        ft[o * 65 + p] = fusedT[(b * CC + o) * LL + t0 + p];
    }
    __syncthreads();
    float s = 0.f, s2 = 0.f;
    #pragma unroll
    for (int j = 0; j < 24; ++j) {
        float v = ft[(wv * 24 + j) * 65 + lane];
        s += v; s2 += v * v;
    }
    ps[wv][lane] = s; ps2[wv][lane] = s2;
    __syncthreads();
    float st = 0.f, st2 = 0.f;
    #pragma unroll
    for (int i = 0; i < 4; ++i) { st += ps[i][lane]; st2 += ps2[i][lane]; }
    float m = st * (1.f / 96.f);
    float inv = rsqrtf(st2 * (1.f / 96.f) - m * m + 1e-5f);
    #pragma unroll
    for (int j = 0; j < 24; ++j) {
        int o = wv * 24 + j;
        res[lane * 97 + o] = (ft[o * 65 + lane] - m) * inv * flg[o] + flb[o];
    }
    __syncthreads();
    const float* xb = x + (b * LL + t0) * CC;
    float* ob = out + (b * LL + t0) * CC;
    for (int e = threadIdx.x; e < 64 * CC; e += 256) {
        int pl = e / CC, o = e % CC;
        ob[e] = xb[e] + res[pl * 97 + o];
    }
}

extern "C" void kernel_launch(void* const* d_in, const int* in_sizes, int n_in,
                              void* d_out, int out_size, void* d_ws, size_t ws_size,
                              hipStream_t stream) {
    const float* x        = (const float*)d_in[0];
    const float* dw_w     = (const float*)d_in[1];
    const float* dw_b     = (const float*)d_in[2];
    const float* bn1_g    = (const float*)d_in[3];
    const float* bn1_b    = (const float*)d_in[4];
    const float* bn1_m    = (const float*)d_in[5];
    const float* bn1_v    = (const float*)d_in[6];
    const float* pw_w     = (const float*)d_in[7];
    const float* pw_b     = (const float*)d_in[8];
    const float* bn2_g    = (const float*)d_in[9];
    const float* bn2_b    = (const float*)d_in[10];
    const float* bn2_m    = (const float*)d_in[11];
    const float* bn2_v    = (const float*)d_in[12];
    const float* ln_g     = (const float*)d_in[13];
    const float* ln_b     = (const float*)d_in[14];
    const float* ipw      = (const float*)d_in[15];
    const float* conv_w   = (const float*)d_in[16];
    const float* conv_b   = (const float*)d_in[17];
    const float* xpw      = (const float*)d_in[18];
    const float* dtw      = (const float*)d_in[19];
    const float* dtb      = (const float*)d_in[20];
    const float* A_logs   = (const float*)d_in[21];
    const float* Ds       = (const float*)d_in[22];
    const float* ong      = (const float*)d_in[23];
    const float* onb      = (const float*)d_in[24];
    const float* opw      = (const float*)d_in[25];
    const float* fus_w    = (const float*)d_in[26];
    const float* fus_b    = (const float*)d_in[27];
    const float* flg      = (const float*)d_in[28];
    const float* flb      = (const float*)d_in[29];

    float* ws = (float*)d_ws;
    float* conv_out = ws + OFF_CONV;
    float* xm_raw   = ws + OFF_XMRAW;
    float* z_buf    = ws + OFF_Z;
    float* v1       = ws + OFF_V1;
    float* v2       = ws + OFF_V2;
    float* dt_s     = ws + OFF_DT;
    float* B_s      = ws + OFF_BS;
    float* C_s      = ws + OFF_CS;
    float* y_scan   = ws + OFF_Y;
    float* y13t     = ws + OFF_Y13;
    float* t_buf    = ws + OFF_T;
    float* W2       = ws + OFF_W2;
    // Aliases (lifetime-disjoint):
    float* cbuf     = y13t;            // k1a/k1b scratch (before scan)
    float* hl_buf   = y13t;            // hlast -> (in-place) hin; 8*98*3072 == y13t size exactly
    float* Tbuf     = xm_raw;          // chunk dt totals (xm_raw dead after k3)
    float* negA     = B_s;             // B_s dead after k5a
    float* fusedT   = y13t;            // after k6 consumed y13t
    float* out      = (float*)d_out;

    k0_w2<<<dim3((CC * DI + 63) / 64), dim3(64), 0, stream>>>(fus_w, opw, W2);
    k1a_dw<<<dim3((BZ * LL * CC + 255) / 256), dim3(256), 0, stream>>>(x, dw_w, dw_b,
                                                     bn1_g, bn1_b, bn1_m, bn1_v, cbuf);
    k1b_pw<<<dim3(NT, BZ), dim3(256), 0, stream>>>(cbuf, pw_w, pw_b,
                                                   bn2_g, bn2_b, bn2_m, bn2_v, conv_out);
    k2_inproj<<<dim3(NT, 4, BZ), dim3(256), 0, stream>>>(x, ln_g, ln_b, ipw, xm_raw, z_buf);
    k3_dw<<<dim3(BZ * DI, 2), dim3(256), 0, stream>>>(xm_raw, conv_w, conv_b, v1, v2);
    k4_proj<<<dim3(NT, 4, BZ), dim3(256), 0, stream>>>(v1, v2, xpw, dtw, dtb, dt_s, B_s, C_s);
    k5a_scan<<<dim3(3 * NCH, 4, BZ), dim3(64), 0, stream>>>(dt_s, B_s, C_s, v1, v2, A_logs,
                                                            y_scan, hl_buf, Tbuf);
    k0c_negA<<<dim3(48), dim3(256), 0, stream>>>(A_logs, negA);
    k5c_comb<<<dim3(48, 4, BZ), dim3(64), 0, stream>>>(hl_buf, Tbuf, negA);
    k5d_corr<<<dim3(NCH - 1, 4, BZ), dim3(256), 0, stream>>>(dt_s, C_s, hl_buf, negA, y_scan);
    k5b_tr<<<dim3(BZ * 2 * DI), dim3(256), 0, stream>>>(y_scan, y13t);
    k6_gather<<<dim3(2 * NT, BZ), dim3(256), 0, stream>>>(y_scan, y13t, v1, z_buf, Ds, ong, onb, t_buf);
    k7a_mm<<<dim3(NT, 4, BZ), dim3(256), 0, stream>>>(t_buf, conv_out, W2, fus_w, fus_b, fusedT);
    k7b_ln<<<dim3(NT, BZ), dim3(256), 0, stream>>>(fusedT, flg, flb, x, out);
}